// Round 6
// baseline (299.719 us; speedup 1.0000x reference)
//
#include <hip/hip_runtime.h>

// ---------------------------------------------------------------- constants
static constexpr int Bn   = 8;
static constexpr int S    = 1024;
static constexpr int FT   = 16;
static constexpr int FDZ  = 768;
static constexpr int INK  = 784;   // FDZ + FT
static constexpr int KP   = 800;   // padded K for dense GEMM (25 * 32)
static constexpr int FDEC = 1024;
static constexpr int M    = Bn * S;   // 8192 rows
static constexpr int H    = 16;
static constexpr int FD   = 16;

typedef __bf16 bf16x8 __attribute__((ext_vector_type(8)));
typedef float  f32x4  __attribute__((ext_vector_type(4)));

__device__ __forceinline__ unsigned short f2b(float f) {
  return __builtin_bit_cast(unsigned short, static_cast<__bf16>(f));
}

__device__ __forceinline__ void gload16(const void* g, void* l) {
  __builtin_amdgcn_global_load_lds(
      (const __attribute__((address_space(1))) unsigned int*)g,
      (__attribute__((address_space(3))) unsigned int*)l, 16, 0, 0);
}

// ---------------------------------------------------------------- prep kernels
__global__ __launch_bounds__(256) void k_prep_xin(const float* __restrict__ z,
                                                  const float* __restrict__ rt,
                                                  unsigned short* __restrict__ xin) {
  int idx = blockIdx.x * 256 + threadIdx.x;
  if (idx >= M * KP) return;
  int m = idx / KP, c = idx - m * KP;
  float v = 0.f;
  if (c < FT)       v = rt[m * FT + c];
  else if (c < INK) v = z[(m >> 10) * FDZ + (c - FT)];
  xin[idx] = f2b(v);
}

__global__ __launch_bounds__(256) void k_cvt_pad(const float* __restrict__ src,
                                                 unsigned short* __restrict__ dst,
                                                 int R, int C, int Cp) {
  int idx = blockIdx.x * 256 + threadIdx.x;
  if (idx >= R * Cp) return;
  int r = idx / Cp, c = idx - r * Cp;
  dst[idx] = (c < C) ? f2b(src[(size_t)r * C + c]) : (unsigned short)0;
}

__global__ __launch_bounds__(256) void k_b3(const float* __restrict__ bq,
                                            const float* __restrict__ bk,
                                            const float* __restrict__ bv,
                                            float* __restrict__ b3) {
  int i = blockIdx.x * 256 + threadIdx.x;
  if (i < 1024)      b3[i] = bq[i];
  else if (i < 2048) b3[i] = bk[i - 1024];
  else if (i < 3072) b3[i] = bv[i - 2048];
}

// ---------------------------------------------------------------- GEMM (C = A @ B^T + bias)
// 256x256 tile, BK=32, 512 thr (8 waves, 4M x 2N, 64x128/wave).
// 3-slot LDS round-robin, depth-2 prefetch via global_load_lds;
// counted s_waitcnt vmcnt(4) (never 0 in main loop) + raw s_barrier.
// 96 KiB LDS -> 1 block/CU; L2 bytes/FLOP halved vs 256x128 (L2-BW was the
// round-5 co-limiter: 256x128 demanded ~28 TB/s of the 34.5 TB/s ceiling).
// Bank swizzle: granule ^= (row>>1)&3 on GLOBAL source (LDS dest linear,
// rule #21) and on ds_read addrs -> 0 conflicts (verified r4/r5).
template<int EPI>
__global__ __launch_bounds__(512, 1) void k_gemm(const unsigned short* __restrict__ A, int lda,
                                                 const unsigned short* __restrict__ Bw, int ldb,
                                                 int K, int N,
                                                 const float* __restrict__ bias,
                                                 float* __restrict__ Cf,
                                                 unsigned short* __restrict__ Cb) {
  __shared__ __align__(16) unsigned short As[3 * 256 * 32];   // 48 KiB
  __shared__ __align__(16) unsigned short Bs[3 * 256 * 32];   // 48 KiB
  const int tid = threadIdx.x, lane = tid & 63, w = tid >> 6;
  const int wr = w >> 1, wc = w & 1;
  const int lr = lane & 15, lg = lane >> 4;

  // XCD-locality map: xcd = bid&7 owns m-tiles [4*xcd, 4*xcd+4), m-fastest
  const int xcd = blockIdx.x & 7;
  const int j   = blockIdx.x >> 3;
  const int m0  = (xcd * 4 + (j & 3)) * 256;
  const int n0  = (j >> 2) * 256;

  const int nt = K >> 5;   // K-tiles of 32

  // ---- staging source pointers (per-lane, swizzled column granule) ----
  const int g0 = tid;                         // granules 0..511
  const int r0g = g0 >> 2, c0g = (g0 & 3) ^ ((r0g >> 1) & 3);
  const int g1 = tid + 512;                   // granules 512..1023
  const int r1g = g1 >> 2, c1g = (g1 & 3) ^ ((r1g >> 1) & 3);
  const unsigned short* srcA0 = A + (size_t)(m0 + r0g) * lda + c0g * 8;
  const unsigned short* srcA1 = A + (size_t)(m0 + r1g) * lda + c1g * 8;
  const unsigned short* srcB0 = Bw + (size_t)(n0 + r0g) * ldb + c0g * 8;
  const unsigned short* srcB1 = Bw + (size_t)(n0 + r1g) * ldb + c1g * 8;
  const int d0 = (w * 64) * 8;                // wave-uniform LDS elem bases
  const int d1 = (512 + w * 64) * 8;

  // ---- fragment read offsets (swizzled) ----
  int offA[4], offB[8];
#pragma unroll
  for (int mi = 0; mi < 4; mi++) {
    int r = wr * 64 + mi * 16 + lr;
    offA[mi] = r * 32 + (lg ^ ((r >> 1) & 3)) * 8;
  }
#pragma unroll
  for (int ni = 0; ni < 8; ni++) {
    int r = wc * 128 + ni * 16 + lr;
    offB[ni] = r * 32 + (lg ^ ((r >> 1) & 3)) * 8;
  }

  f32x4 acc[4][8];
#pragma unroll
  for (int i = 0; i < 4; i++)
#pragma unroll
    for (int j2 = 0; j2 < 8; j2++)
#pragma unroll
      for (int e = 0; e < 4; e++) acc[i][j2][e] = 0.f;

  auto stage = [&](int tt) {
    const int sl = tt % 3;
    const size_t ko = (size_t)tt * 32;
    gload16(srcA0 + ko, &As[sl * 8192 + d0]);
    gload16(srcA1 + ko, &As[sl * 8192 + d1]);
    gload16(srcB0 + ko, &Bs[sl * 8192 + d0]);
    gload16(srcB1 + ko, &Bs[sl * 8192 + d1]);
  };
  auto compute = [&](int tt) {
    const int sl = (tt % 3) * 8192;
    bf16x8 af[4], bfr[8];
#pragma unroll
    for (int mi = 0; mi < 4; mi++)
      af[mi] = *reinterpret_cast<const bf16x8*>(&As[sl + offA[mi]]);
#pragma unroll
    for (int ni = 0; ni < 8; ni++)
      bfr[ni] = *reinterpret_cast<const bf16x8*>(&Bs[sl + offB[ni]]);
    __builtin_amdgcn_s_setprio(1);
#pragma unroll
    for (int mi = 0; mi < 4; mi++)
#pragma unroll
      for (int ni = 0; ni < 8; ni++)
        acc[mi][ni] = __builtin_amdgcn_mfma_f32_16x16x32_bf16(af[mi], bfr[ni], acc[mi][ni], 0, 0, 0);
    __builtin_amdgcn_s_setprio(0);
  };

  // prologue: 2 K-tiles in flight
  stage(0); stage(1);

  int t = 0;
  for (; t < nt - 2; ++t) {
    asm volatile("s_waitcnt vmcnt(4)" ::: "memory");   // tile t landed; t+1 in flight
    __builtin_amdgcn_s_barrier();
    stage(t + 2);
    compute(t);
  }
  asm volatile("s_waitcnt vmcnt(4)" ::: "memory");
  __builtin_amdgcn_s_barrier();
  compute(t); ++t;
  asm volatile("s_waitcnt vmcnt(0)" ::: "memory");
  __builtin_amdgcn_s_barrier();
  compute(t);

  // epilogue
#pragma unroll
  for (int mi = 0; mi < 4; mi++)
#pragma unroll
    for (int ni = 0; ni < 8; ni++) {
      int col = n0 + wc * 128 + ni * 16 + lr;
      float bv = bias ? bias[col] : 0.f;
#pragma unroll
      for (int jj = 0; jj < 4; jj++) {
        int row = m0 + wr * 64 + mi * 16 + lg * 4 + jj;
        float v = acc[mi][ni][jj] + bv;
        if constexpr (EPI == 0) {
          Cf[(size_t)row * N + col] = v;
        } else if constexpr (EPI == 1) {
          Cb[(size_t)row * N + col] = f2b(v);
        } else {
          size_t o = (size_t)row * N + col;
          float xv = Cf[o] + v;
          Cf[o] = xv;
          Cb[o] = f2b(xv);
        }
      }
    }
}

// ---------------------------------------------------------------- LayerNorm (per row of 1024)
__global__ __launch_bounds__(256) void k_ln(const float* __restrict__ x,
                                            const float* __restrict__ g,
                                            const float* __restrict__ bta,
                                            unsigned short* __restrict__ xn) {
  int row = blockIdx.x;
  int tid = threadIdx.x;
  const float4 v = *reinterpret_cast<const float4*>(&x[(size_t)row * 1024 + tid * 4]);
  float s = v.x + v.y + v.z + v.w;
  float q = v.x * v.x + v.y * v.y + v.z * v.z + v.w * v.w;
  for (int off = 32; off; off >>= 1) { s += __shfl_down(s, off); q += __shfl_down(q, off); }
  __shared__ float ss[4], qq[4];
  int wid = tid >> 6, lane = tid & 63;
  if (lane == 0) { ss[wid] = s; qq[wid] = q; }
  __syncthreads();
  float St = ss[0] + ss[1] + ss[2] + ss[3];
  float Qt = qq[0] + qq[1] + qq[2] + qq[3];
  float mu  = St * (1.f / 1024.f);
  float var = Qt * (1.f / 1024.f) - mu * mu;
  float rstd = rsqrtf(var + 1e-6f);
  int c = tid * 4;
  unsigned short o[4];
  o[0] = f2b(g[c + 0] * (v.x - mu) * rstd + bta[c + 0]);
  o[1] = f2b(g[c + 1] * (v.y - mu) * rstd + bta[c + 1]);
  o[2] = f2b(g[c + 2] * (v.z - mu) * rstd + bta[c + 2]);
  o[3] = f2b(g[c + 3] * (v.w - mu) * rstd + bta[c + 3]);
  *reinterpret_cast<uint2*>(&xn[(size_t)row * 1024 + c]) = *reinterpret_cast<uint2*>(o);
}

// ---------------------------------------------------------------- flash attention
// grid (128 bh, 4 pairs); 512 thr = 8 waves x 16 q-rows. Block does q-tiles {y, 7-y}
// (balanced 18 k-tiles). Swapped QK^T: lane holds 16 scores of ONE q-row ->
// in-register softmax + 2 shuffles. Async reg-prefetch of next K/V tile.
__global__ __launch_bounds__(512, 4) void k_attn(const unsigned short* __restrict__ qkv,
                                                 unsigned short* __restrict__ o) {
  __shared__ unsigned short Ks[64][72];
  __shared__ unsigned short Vt[64][72];      // Vt[d][swz(k)], swz: k-blk ^= (d>>3)
  __shared__ unsigned short Pl[8][16][72];
  const int tid = threadIdx.x, lane = tid & 63, w = tid >> 6;
  const int bh = blockIdx.x, b = bh >> 4, h = bh & 15;
  const int lr = lane & 15, lg = lane >> 4, lg4 = lg * 4;
  const int krow = tid >> 3, c8 = (tid & 7) << 3;
  const int kb8 = krow >> 3, kl = krow & 7, vq = tid & 7;
  const float slope2 = exp2f(-0.5f * (float)(h + 1)) * 1.44269504f;
  const float sc2 = 0.125f * 1.44269504f;

  for (int ph = 0; ph < 2; ++ph) {
    const int qb = ph ? (7 - (int)blockIdx.y) : (int)blockIdx.y;
    const int q0 = qb * 128;
    const int qlo = q0 + w * 16;
    const int qa = qlo + lr;                 // this lane's q-row (for scores)

    bf16x8 qf[2];
    {
      const unsigned short* qp = &qkv[(size_t)(b * 1024 + qlo + lr) * 3072 + h * 64];
      qf[0] = *reinterpret_cast<const bf16x8*>(qp + lg * 8);
      qf[1] = *reinterpret_cast<const bf16x8*>(qp + 32 + lg * 8);
    }
    float mrun = -3.0e38f, lrun = 0.f;
    f32x4 accO[4];
    for (int dn = 0; dn < 4; dn++)
      for (int e = 0; e < 4; e++) accO[dn][e] = 0.f;

    const int nt = 2 * qb + 2;
    uint4 kr, vr;
    {
      const size_t base = (size_t)(b * 1024 + krow) * 3072 + h * 64;
      kr = *reinterpret_cast<const uint4*>(&qkv[base + 1024 + c8]);
      vr = *reinterpret_cast<const uint4*>(&qkv[base + 2048 + c8]);
    }
    for (int kt = 0; kt < nt; ++kt) {
      const int kb = kt << 6;
      __syncthreads();                        // prior tile's readers done
      *reinterpret_cast<uint4*>(&Ks[krow][c8]) = kr;
      {
        const unsigned short* vs = reinterpret_cast<const unsigned short*>(&vr);
        for (int j = 0; j < 8; j++)
          Vt[c8 + j][((kb8 ^ vq) << 3) | kl] = vs[j];
      }
      __syncthreads();                        // LDS ready
      if (kt + 1 < nt) {                      // prefetch next tile under compute
        const size_t base = (size_t)(b * 1024 + kb + 64 + krow) * 3072 + h * 64;
        kr = *reinterpret_cast<const uint4*>(&qkv[base + 1024 + c8]);
        vr = *reinterpret_cast<const uint4*>(&qkv[base + 2048 + c8]);
      }
      if (kb <= qlo + 15) {                   // wave-uniform skip of fully-masked tile
        f32x4 sf[4];
        for (int kn = 0; kn < 4; kn++) {
          f32x4 zz;
          for (int e = 0; e < 4; e++) zz[e] = 0.f;
          bf16x8 kf0 = *reinterpret_cast<const bf16x8*>(&Ks[kn * 16 + lr][lg * 8]);
          bf16x8 kf1 = *reinterpret_cast<const bf16x8*>(&Ks[kn * 16 + lr][32 + lg * 8]);
          zz = __builtin_amdgcn_mfma_f32_16x16x32_bf16(kf0, qf[0], zz, 0, 0, 0);
          zz = __builtin_amdgcn_mfma_f32_16x16x32_bf16(kf1, qf[1], zz, 0, 0, 0);
          sf[kn] = zz;                        // sf[kn][j]: k=kb+kn*16+lg4+j, q=qa
        }
        const bool needmask = (kb + 63 > qlo);
        float sc[4][4];
        float ml = -3.0e38f;
        for (int kn = 0; kn < 4; kn++) {
          float alib = slope2 * (float)(kb + kn * 16 + lg4);
          for (int j = 0; j < 4; j++) {
            float v = fmaf(sf[kn][j], sc2, alib + slope2 * (float)j);
            if (needmask && (kb + kn * 16 + lg4 + j > qa)) v = -3.0e38f;
            sc[kn][j] = v;
            ml = fmaxf(ml, v);
          }
        }
        ml = fmaxf(ml, __shfl_xor(ml, 16));
        ml = fmaxf(ml, __shfl_xor(ml, 32));
        float mnew = fmaxf(mrun, ml);
        float f = exp2f(mrun - mnew);
        float rs = 0.f;
        for (int kn = 0; kn < 4; kn++) {
          __bf16 pb[4];
          for (int j = 0; j < 4; j++) {
            float pv = exp2f(sc[kn][j] - mnew);
            rs += pv;
            pb[j] = (__bf16)pv;
          }
          *reinterpret_cast<uint2*>(&Pl[w][lr][kn * 16 + lg4]) =
              *reinterpret_cast<uint2*>(pb);
        }
        rs += __shfl_xor(rs, 16);
        rs += __shfl_xor(rs, 32);
        lrun = lrun * f + rs;
        mrun = mnew;
        float fj[4];
        for (int j = 0; j < 4; j++) fj[j] = __shfl(f, (lane & 48) | (lg4 + j));
        for (int dn = 0; dn < 4; dn++)
          for (int j = 0; j < 4; j++) accO[dn][j] *= fj[j];
        asm volatile("s_waitcnt lgkmcnt(0)" ::: "memory");   // own P writes drained
        for (int ks = 0; ks < 2; ks++) {
          bf16x8 pa = *reinterpret_cast<const bf16x8*>(&Pl[w][lr][ks * 32 + lg * 8]);
          for (int dn = 0; dn < 4; dn++) {
            int d = dn * 16 + lr;
            bf16x8 vb = *reinterpret_cast<const bf16x8*>(
                &Vt[d][(((ks * 4 + lg) ^ (d >> 3)) << 3)]);
            accO[dn] = __builtin_amdgcn_mfma_f32_16x16x32_bf16(pa, vb, accO[dn], 0, 0, 0);
          }
        }
      }
    }
    float linv[4];
    for (int j = 0; j < 4; j++)
      linv[j] = 1.f / __shfl(lrun, (lane & 48) | (lg4 + j));
    for (int dn = 0; dn < 4; dn++)
      for (int j = 0; j < 4; j++) {
        int row = qlo + lg4 + j;
        int d = dn * 16 + lr;
        o[(size_t)(b * 1024 + row) * 1024 + h * 64 + d] = f2b(accO[dn][j] * linv[j]);
      }
  }
}

// ---------------------------------------------------------------- decode GEMM (N=16) + transpose
__global__ __launch_bounds__(256) void k_dec(const unsigned short* __restrict__ xb,
                                             const unsigned short* __restrict__ dw,
                                             const float* __restrict__ db,
                                             float* __restrict__ out) {
  const int tid = threadIdx.x, lane = tid & 63, w = tid >> 6;
  const int lr = lane & 15, lg = lane >> 4;
  const int sb = blockIdx.x * 4 + w;
  const int r0 = sb * 16;
  f32x4 acc;
  for (int e = 0; e < 4; e++) acc[e] = 0.f;
  const unsigned short* arow = &xb[(size_t)(r0 + lr) * 1024];
  const unsigned short* brow = &dw[(size_t)lr * 1024];
  for (int k0 = 0; k0 < 1024; k0 += 32) {
    bf16x8 af = *reinterpret_cast<const bf16x8*>(arow + k0 + lg * 8);
    bf16x8 bf = *reinterpret_cast<const bf16x8*>(brow + k0 + lg * 8);
    acc = __builtin_amdgcn_mfma_f32_16x16x32_bf16(af, bf, acc, 0, 0, 0);
  }
  const int b = r0 >> 10;
  const int sl = (r0 & 1023) + lg * 4;
  float bias = db[lr];
  float4 res;
  res.x = acc[0] + bias; res.y = acc[1] + bias; res.z = acc[2] + bias; res.w = acc[3] + bias;
  *reinterpret_cast<float4*>(&out[(size_t)(b * 16 + lr) * 1024 + sl]) = res;
}

// ---------------------------------------------------------------- launcher
extern "C" void kernel_launch(void* const* d_in, const int* in_sizes, int n_in,
                              void* d_out, int out_size, void* d_ws, size_t ws_size,
                              hipStream_t stream) {
  (void)in_sizes; (void)n_in; (void)out_size;
  const float* z   = (const float*)d_in[0];
  const float* rt  = (const float*)d_in[1];
  const float* dnw = (const float*)d_in[2];
  const float* dnb = (const float*)d_in[3];
  const float* lng = (const float*)d_in[4];
  const float* lnb = (const float*)d_in[5];
  const float* wq  = (const float*)d_in[6];
  const float* bq  = (const float*)d_in[7];
  const float* wk  = (const float*)d_in[8];
  const float* bk  = (const float*)d_in[9];
  const float* wv  = (const float*)d_in[10];
  const float* bv  = (const float*)d_in[11];
  const float* wo  = (const float*)d_in[12];
  const float* bo  = (const float*)d_in[13];
  const float* dcw = (const float*)d_in[14];
  const float* dcb = (const float*)d_in[15];
  float* out = (float*)d_out;

  char* p = (char*)d_ws;
  float* x            = (float*)p;          p += (size_t)M * FDEC * 4;
  unsigned short* xin = (unsigned short*)p; p += (size_t)M * KP * 2;
  unsigned short* wdn = (unsigned short*)p; p += (size_t)FDEC * KP * 2;
  unsigned short* xn  = (unsigned short*)p; p += (size_t)M * FDEC * 2;
  unsigned short* w3  = (unsigned short*)p; p += (size_t)3 * FDEC * FDEC * 2;
  float* b3           = (float*)p;          p += (size_t)3 * FDEC * 4;
  unsigned short* qkv = (unsigned short*)p; p += (size_t)M * 3 * FDEC * 2;
  unsigned short* ob  = (unsigned short*)p; p += (size_t)M * FDEC * 2;
  unsigned short* wob = (unsigned short*)p; p += (size_t)FDEC * FDEC * 2;
  unsigned short* dwb = (unsigned short*)p; p += (size_t)FD * FDEC * 2;
  if ((size_t)(p - (char*)d_ws) > ws_size) return;

  k_prep_xin<<<(M * KP) / 256, 256, 0, stream>>>(z, rt, xin);
  k_cvt_pad<<<(FDEC * KP) / 256, 256, 0, stream>>>(dnw, wdn, FDEC, INK, KP);
  k_cvt_pad<<<(FDEC * FDEC) / 256, 256, 0, stream>>>(wq, w3, FDEC, FDEC, FDEC);
  k_cvt_pad<<<(FDEC * FDEC) / 256, 256, 0, stream>>>(wk, w3 + FDEC * FDEC, FDEC, FDEC, FDEC);
  k_cvt_pad<<<(FDEC * FDEC) / 256, 256, 0, stream>>>(wv, w3 + 2 * FDEC * FDEC, FDEC, FDEC, FDEC);
  k_cvt_pad<<<(FDEC * FDEC) / 256, 256, 0, stream>>>(wo, wob, FDEC, FDEC, FDEC);
  k_cvt_pad<<<(FD * FDEC) / 256, 256, 0, stream>>>(dcw, dwb, FD, FDEC, FDEC);
  k_b3<<<12, 256, 0, stream>>>(bq, bk, bv, b3);

  // grids: 1D, bid&7 = XCD, per-XCD chunk = 4 m-tiles x all n-tiles (m fastest)
  k_gemm<0><<<(M / 256) * (FDEC / 256), 512, 0, stream>>>(xin, KP, wdn, KP, KP, FDEC, dnb, x, nullptr);
  k_ln<<<M, 256, 0, stream>>>(x, lng, lnb, xn);
  k_gemm<1><<<(M / 256) * (3 * FDEC / 256), 512, 0, stream>>>(xn, FDEC, w3, FDEC, FDEC, 3 * FDEC, b3, nullptr, qkv);
  k_attn<<<dim3(Bn * H, 4), 512, 0, stream>>>(qkv, ob);
  k_gemm<2><<<(M / 256) * (FDEC / 256), 512, 0, stream>>>(ob, FDEC, wob, FDEC, FDEC, FDEC, bo, x, xn);
  k_dec<<<M / 64, 256, 0, stream>>>(xn, dwb, dcb, out);
}

// Round 7
// 268.760 us; speedup vs baseline: 1.1152x; 1.1152x over previous
//
#include <hip/hip_runtime.h>

// ---------------------------------------------------------------- constants
static constexpr int Bn   = 8;
static constexpr int S    = 1024;
static constexpr int FT   = 16;
static constexpr int FDZ  = 768;
static constexpr int INK  = 784;   // FDZ + FT
static constexpr int KP   = 800;   // padded K for dense GEMM (25 * 32)
static constexpr int FDEC = 1024;
static constexpr int M    = Bn * S;   // 8192 rows
static constexpr int H    = 16;
static constexpr int FD   = 16;

typedef __bf16 bf16x8 __attribute__((ext_vector_type(8)));
typedef float  f32x4  __attribute__((ext_vector_type(4)));

__device__ __forceinline__ unsigned short f2b(float f) {
  return __builtin_bit_cast(unsigned short, static_cast<__bf16>(f));
}

__device__ __forceinline__ void gload16(const void* g, void* l) {
  __builtin_amdgcn_global_load_lds(
      (const __attribute__((address_space(1))) unsigned int*)g,
      (__attribute__((address_space(3))) unsigned int*)l, 16, 0, 0);
}

// ---------------------------------------------------------------- prep kernels
__global__ __launch_bounds__(256) void k_prep_xin(const float* __restrict__ z,
                                                  const float* __restrict__ rt,
                                                  unsigned short* __restrict__ xin) {
  int idx = blockIdx.x * 256 + threadIdx.x;
  if (idx >= M * KP) return;
  int m = idx / KP, c = idx - m * KP;
  float v = 0.f;
  if (c < FT)       v = rt[m * FT + c];
  else if (c < INK) v = z[(m >> 10) * FDZ + (c - FT)];
  xin[idx] = f2b(v);
}

__global__ __launch_bounds__(256) void k_cvt_pad(const float* __restrict__ src,
                                                 unsigned short* __restrict__ dst,
                                                 int R, int C, int Cp) {
  int idx = blockIdx.x * 256 + threadIdx.x;
  if (idx >= R * Cp) return;
  int r = idx / Cp, c = idx - r * Cp;
  dst[idx] = (c < C) ? f2b(src[(size_t)r * C + c]) : (unsigned short)0;
}

__global__ __launch_bounds__(256) void k_b3(const float* __restrict__ bq,
                                            const float* __restrict__ bk,
                                            const float* __restrict__ bv,
                                            float* __restrict__ b3) {
  int i = blockIdx.x * 256 + threadIdx.x;
  if (i < 1024)      b3[i] = bq[i];
  else if (i < 2048) b3[i] = bk[i - 1024];
  else if (i < 3072) b3[i] = bv[i - 2048];
}

// ---------------------------------------------------------------- GEMM 2-phase (r5: 256x128, 2 blk/CU)
template<int EPI>
__global__ __launch_bounds__(512, 4) void k_gemm2(const unsigned short* __restrict__ A, int lda,
                                                  const unsigned short* __restrict__ Bw, int ldb,
                                                  int K, int N,
                                                  const float* __restrict__ bias,
                                                  float* __restrict__ Cf,
                                                  unsigned short* __restrict__ Cb) {
  __shared__ __align__(16) unsigned short As[3 * 256 * 32];   // 48 KiB
  __shared__ __align__(16) unsigned short Bs[3 * 128 * 32];   // 24 KiB
  const int tid = threadIdx.x, lane = tid & 63, w = tid >> 6;
  const int wr = w >> 1, wc = w & 1;
  const int lr = lane & 15, lg = lane >> 4;

  const int xcd = blockIdx.x & 7;
  const int j   = blockIdx.x >> 3;
  const int m0  = (xcd * 4 + (j & 3)) * 256;
  const int n0  = (j >> 2) * 128;

  const int nt = K >> 5;

  const int giA0 = w * 64 + lane;
  const int rA0 = giA0 >> 2, cA0 = (giA0 & 3) ^ ((rA0 >> 1) & 3);
  const int giA1 = 512 + w * 64 + lane;
  const int rA1 = giA1 >> 2, cA1 = (giA1 & 3) ^ ((rA1 >> 1) & 3);
  const int giB0 = w * 64 + lane;
  const int rB0 = giB0 >> 2, cB0 = (giB0 & 3) ^ ((rB0 >> 1) & 3);
  const unsigned short* srcA0 = A + (size_t)(m0 + rA0) * lda + cA0 * 8;
  const unsigned short* srcA1 = A + (size_t)(m0 + rA1) * lda + cA1 * 8;
  const unsigned short* srcB0 = Bw + (size_t)(n0 + rB0) * ldb + cB0 * 8;
  const int dA0 = (w * 64) * 8;
  const int dA1 = (512 + w * 64) * 8;
  const int dB0 = (w * 64) * 8;

  int offA[4], offB[4];
#pragma unroll
  for (int mi = 0; mi < 4; mi++) {
    int r = wr * 64 + mi * 16 + lr;
    offA[mi] = r * 32 + (lg ^ ((r >> 1) & 3)) * 8;
  }
#pragma unroll
  for (int ni = 0; ni < 4; ni++) {
    int r = wc * 64 + ni * 16 + lr;
    offB[ni] = r * 32 + (lg ^ ((r >> 1) & 3)) * 8;
  }

  f32x4 acc[4][4];
#pragma unroll
  for (int i = 0; i < 4; i++)
#pragma unroll
    for (int j2 = 0; j2 < 4; j2++)
#pragma unroll
      for (int e = 0; e < 4; e++) acc[i][j2][e] = 0.f;

  auto stage = [&](int tt) {
    const int sl = tt % 3;
    const size_t ko = (size_t)tt * 32;
    gload16(srcA0 + ko, &As[sl * 8192 + dA0]);
    gload16(srcA1 + ko, &As[sl * 8192 + dA1]);
    gload16(srcB0 + ko, &Bs[sl * 4096 + dB0]);
  };
  auto compute = [&](int tt) {
    const int sa = (tt % 3) * 8192;
    const int sb = (tt % 3) * 4096;
    bf16x8 af[4], bfr[4];
#pragma unroll
    for (int mi = 0; mi < 4; mi++)
      af[mi] = *reinterpret_cast<const bf16x8*>(&As[sa + offA[mi]]);
#pragma unroll
    for (int ni = 0; ni < 4; ni++)
      bfr[ni] = *reinterpret_cast<const bf16x8*>(&Bs[sb + offB[ni]]);
    __builtin_amdgcn_s_setprio(1);
#pragma unroll
    for (int mi = 0; mi < 4; mi++)
#pragma unroll
      for (int ni = 0; ni < 4; ni++)
        acc[mi][ni] = __builtin_amdgcn_mfma_f32_16x16x32_bf16(af[mi], bfr[ni], acc[mi][ni], 0, 0, 0);
    __builtin_amdgcn_s_setprio(0);
  };

  stage(0); stage(1);

  int t = 0;
  for (; t < nt - 2; ++t) {
    asm volatile("s_waitcnt vmcnt(3)" ::: "memory");
    __builtin_amdgcn_s_barrier();
    stage(t + 2);
    compute(t);
  }
  asm volatile("s_waitcnt vmcnt(3)" ::: "memory");
  __builtin_amdgcn_s_barrier();
  compute(t); ++t;
  asm volatile("s_waitcnt vmcnt(0)" ::: "memory");
  __builtin_amdgcn_s_barrier();
  compute(t);

#pragma unroll
  for (int mi = 0; mi < 4; mi++)
#pragma unroll
    for (int ni = 0; ni < 4; ni++) {
      int col = n0 + wc * 64 + ni * 16 + lr;
      float bv = bias ? bias[col] : 0.f;
#pragma unroll
      for (int jj = 0; jj < 4; jj++) {
        int row = m0 + wr * 64 + mi * 16 + lg * 4 + jj;
        float v = acc[mi][ni][jj] + bv;
        if constexpr (EPI == 0) {
          Cf[(size_t)row * N + col] = v;
        } else if constexpr (EPI == 1) {
          Cb[(size_t)row * N + col] = f2b(v);
        } else {
          size_t o = (size_t)row * N + col;
          float xv = Cf[o] + v;
          Cf[o] = xv;
          Cb[o] = f2b(xv);
        }
      }
    }
}

// ---------------------------------------------------------------- GEMM 4-phase (256x256, T3+T4+T5)
// Same 3-slot/depth-2 gating + zero-conflict swizzle as r6, but each K-tile is
// split into 4 quadrant phases {6 ds_read || 1 stage -> lgkmcnt(0) ->
// setprio(1) 8 MFMA setprio(0) -> barrier}; counted vmcnt(4) once per K-tile.
template<int EPI>
__global__ __launch_bounds__(512, 1) void k_gemm4(const unsigned short* __restrict__ A, int lda,
                                                  const unsigned short* __restrict__ Bw, int ldb,
                                                  int K, int N,
                                                  const float* __restrict__ bias,
                                                  float* __restrict__ Cf,
                                                  unsigned short* __restrict__ Cb) {
  __shared__ __align__(16) unsigned short As[3 * 256 * 32];   // 48 KiB
  __shared__ __align__(16) unsigned short Bs[3 * 256 * 32];   // 48 KiB
  const int tid = threadIdx.x, lane = tid & 63, w = tid >> 6;
  const int wr = w >> 1, wc = w & 1;
  const int lr = lane & 15, lg = lane >> 4;

  const int xcd = blockIdx.x & 7;
  const int j   = blockIdx.x >> 3;
  const int m0  = (xcd * 4 + (j & 3)) * 256;
  const int n0  = (j >> 2) * 256;

  const int nt = K >> 5;

  const int g0 = tid;
  const int r0g = g0 >> 2, c0g = (g0 & 3) ^ ((r0g >> 1) & 3);
  const int g1 = tid + 512;
  const int r1g = g1 >> 2, c1g = (g1 & 3) ^ ((r1g >> 1) & 3);
  const unsigned short* srcA0 = A + (size_t)(m0 + r0g) * lda + c0g * 8;
  const unsigned short* srcA1 = A + (size_t)(m0 + r1g) * lda + c1g * 8;
  const unsigned short* srcB0 = Bw + (size_t)(n0 + r0g) * ldb + c0g * 8;
  const unsigned short* srcB1 = Bw + (size_t)(n0 + r1g) * ldb + c1g * 8;
  const int d0 = (w * 64) * 8;
  const int d1 = (512 + w * 64) * 8;

  int offA[4], offB[8];
#pragma unroll
  for (int mi = 0; mi < 4; mi++) {
    int r = wr * 64 + mi * 16 + lr;
    offA[mi] = r * 32 + (lg ^ ((r >> 1) & 3)) * 8;
  }
#pragma unroll
  for (int ni = 0; ni < 8; ni++) {
    int r = wc * 128 + ni * 16 + lr;
    offB[ni] = r * 32 + (lg ^ ((r >> 1) & 3)) * 8;
  }

  f32x4 acc[4][8];
#pragma unroll
  for (int i = 0; i < 4; i++)
#pragma unroll
    for (int j2 = 0; j2 < 8; j2++)
#pragma unroll
      for (int e = 0; e < 4; e++) acc[i][j2][e] = 0.f;

  // 4-phase K-tile body. dostage: issue 1 of tile (tt+2)'s 4 loads per phase.
  // endgate: -1 none, 0/4 -> s_waitcnt vmcnt(N) before the final barrier.
  auto compute4 = [&](int tt, bool dostage, int endgate) {
    const int sl = (tt % 3) * 8192;
    const int s2 = ((tt + 2) % 3) * 8192;
    const size_t ko = (size_t)(tt + 2) * 32;
#pragma unroll
    for (int p = 0; p < 4; ++p) {
      const int mh = p >> 1, nh = p & 1;
      bf16x8 af[2], bfr[4];
#pragma unroll
      for (int i = 0; i < 2; i++)
        af[i] = *reinterpret_cast<const bf16x8*>(&As[sl + offA[2 * mh + i]]);
#pragma unroll
      for (int i = 0; i < 4; i++)
        bfr[i] = *reinterpret_cast<const bf16x8*>(&Bs[sl + offB[4 * nh + i]]);
      if (dostage) {
        if (p == 0) gload16(srcA0 + ko, &As[s2 + d0]);
        else if (p == 1) gload16(srcA1 + ko, &As[s2 + d1]);
        else if (p == 2) gload16(srcB0 + ko, &Bs[s2 + d0]);
        else gload16(srcB1 + ko, &Bs[s2 + d1]);
      }
      asm volatile("s_waitcnt lgkmcnt(0)" ::: "memory");
      __builtin_amdgcn_s_setprio(1);
#pragma unroll
      for (int i = 0; i < 2; i++)
#pragma unroll
        for (int jn = 0; jn < 4; jn++)
          acc[2 * mh + i][4 * nh + jn] = __builtin_amdgcn_mfma_f32_16x16x32_bf16(
              af[i], bfr[jn], acc[2 * mh + i][4 * nh + jn], 0, 0, 0);
      __builtin_amdgcn_s_setprio(0);
      if (p == 3) {
        if (endgate == 4) asm volatile("s_waitcnt vmcnt(4)" ::: "memory");
        else if (endgate == 0) asm volatile("s_waitcnt vmcnt(0)" ::: "memory");
      }
      __builtin_amdgcn_s_barrier();
    }
  };

  // prologue: tiles 0 and 1 staged (8 loads/wave); gate tile 0 (retire its 4)
  {
    const size_t ko0 = 0, ko1 = 32;
    gload16(srcA0 + ko0, &As[d0]); gload16(srcA1 + ko0, &As[d1]);
    gload16(srcB0 + ko0, &Bs[d0]); gload16(srcB1 + ko0, &Bs[d1]);
    gload16(srcA0 + ko1, &As[8192 + d0]); gload16(srcA1 + ko1, &As[8192 + d1]);
    gload16(srcB0 + ko1, &Bs[8192 + d0]); gload16(srcB1 + ko1, &Bs[8192 + d1]);
    asm volatile("s_waitcnt vmcnt(4)" ::: "memory");
    __builtin_amdgcn_s_barrier();
  }

  int t = 0;
  for (; t < nt - 2; ++t)
    compute4(t, true, 4);       // stage t+2; end-gate retires tile t+1
  compute4(t, false, 0); ++t;   // tile nt-2: end-gate drains tile nt-1
  compute4(t, false, -1);       // tile nt-1

#pragma unroll
  for (int mi = 0; mi < 4; mi++)
#pragma unroll
    for (int ni = 0; ni < 8; ni++) {
      int col = n0 + wc * 128 + ni * 16 + lr;
      float bv = bias ? bias[col] : 0.f;
#pragma unroll
      for (int jj = 0; jj < 4; jj++) {
        int row = m0 + wr * 64 + mi * 16 + lg * 4 + jj;
        float v = acc[mi][ni][jj] + bv;
        if constexpr (EPI == 0) {
          Cf[(size_t)row * N + col] = v;
        } else if constexpr (EPI == 1) {
          Cb[(size_t)row * N + col] = f2b(v);
        } else {
          size_t o = (size_t)row * N + col;
          float xv = Cf[o] + v;
          Cf[o] = xv;
          Cb[o] = f2b(xv);
        }
      }
    }
}

// ---------------------------------------------------------------- LayerNorm (per row of 1024)
__global__ __launch_bounds__(256) void k_ln(const float* __restrict__ x,
                                            const float* __restrict__ g,
                                            const float* __restrict__ bta,
                                            unsigned short* __restrict__ xn) {
  int row = blockIdx.x;
  int tid = threadIdx.x;
  const float4 v = *reinterpret_cast<const float4*>(&x[(size_t)row * 1024 + tid * 4]);
  float s = v.x + v.y + v.z + v.w;
  float q = v.x * v.x + v.y * v.y + v.z * v.z + v.w * v.w;
  for (int off = 32; off; off >>= 1) { s += __shfl_down(s, off); q += __shfl_down(q, off); }
  __shared__ float ss[4], qq[4];
  int wid = tid >> 6, lane = tid & 63;
  if (lane == 0) { ss[wid] = s; qq[wid] = q; }
  __syncthreads();
  float St = ss[0] + ss[1] + ss[2] + ss[3];
  float Qt = qq[0] + qq[1] + qq[2] + qq[3];
  float mu  = St * (1.f / 1024.f);
  float var = Qt * (1.f / 1024.f) - mu * mu;
  float rstd = rsqrtf(var + 1e-6f);
  int c = tid * 4;
  unsigned short o[4];
  o[0] = f2b(g[c + 0] * (v.x - mu) * rstd + bta[c + 0]);
  o[1] = f2b(g[c + 1] * (v.y - mu) * rstd + bta[c + 1]);
  o[2] = f2b(g[c + 2] * (v.z - mu) * rstd + bta[c + 2]);
  o[3] = f2b(g[c + 3] * (v.w - mu) * rstd + bta[c + 3]);
  *reinterpret_cast<uint2*>(&xn[(size_t)row * 1024 + c]) = *reinterpret_cast<uint2*>(o);
}

// ---------------------------------------------------------------- flash attention
__global__ __launch_bounds__(512, 4) void k_attn(const unsigned short* __restrict__ qkv,
                                                 unsigned short* __restrict__ o) {
  __shared__ unsigned short Ks[64][72];
  __shared__ unsigned short Vt[64][72];
  __shared__ unsigned short Pl[8][16][72];
  const int tid = threadIdx.x, lane = tid & 63, w = tid >> 6;
  const int bh = blockIdx.x, b = bh >> 4, h = bh & 15;
  const int lr = lane & 15, lg = lane >> 4, lg4 = lg * 4;
  const int krow = tid >> 3, c8 = (tid & 7) << 3;
  const int kb8 = krow >> 3, kl = krow & 7, vq = tid & 7;
  const float slope2 = exp2f(-0.5f * (float)(h + 1)) * 1.44269504f;
  const float sc2 = 0.125f * 1.44269504f;

  for (int ph = 0; ph < 2; ++ph) {
    const int qb = ph ? (7 - (int)blockIdx.y) : (int)blockIdx.y;
    const int q0 = qb * 128;
    const int qlo = q0 + w * 16;
    const int qa = qlo + lr;

    bf16x8 qf[2];
    {
      const unsigned short* qp = &qkv[(size_t)(b * 1024 + qlo + lr) * 3072 + h * 64];
      qf[0] = *reinterpret_cast<const bf16x8*>(qp + lg * 8);
      qf[1] = *reinterpret_cast<const bf16x8*>(qp + 32 + lg * 8);
    }
    float mrun = -3.0e38f, lrun = 0.f;
    f32x4 accO[4];
    for (int dn = 0; dn < 4; dn++)
      for (int e = 0; e < 4; e++) accO[dn][e] = 0.f;

    const int nt = 2 * qb + 2;
    uint4 kr, vr;
    {
      const size_t base = (size_t)(b * 1024 + krow) * 3072 + h * 64;
      kr = *reinterpret_cast<const uint4*>(&qkv[base + 1024 + c8]);
      vr = *reinterpret_cast<const uint4*>(&qkv[base + 2048 + c8]);
    }
    for (int kt = 0; kt < nt; ++kt) {
      const int kb = kt << 6;
      __syncthreads();
      *reinterpret_cast<uint4*>(&Ks[krow][c8]) = kr;
      {
        const unsigned short* vs = reinterpret_cast<const unsigned short*>(&vr);
        for (int j = 0; j < 8; j++)
          Vt[c8 + j][((kb8 ^ vq) << 3) | kl] = vs[j];
      }
      __syncthreads();
      if (kt + 1 < nt) {
        const size_t base = (size_t)(b * 1024 + kb + 64 + krow) * 3072 + h * 64;
        kr = *reinterpret_cast<const uint4*>(&qkv[base + 1024 + c8]);
        vr = *reinterpret_cast<const uint4*>(&qkv[base + 2048 + c8]);
      }
      if (kb <= qlo + 15) {
        f32x4 sf[4];
        for (int kn = 0; kn < 4; kn++) {
          f32x4 zz;
          for (int e = 0; e < 4; e++) zz[e] = 0.f;
          bf16x8 kf0 = *reinterpret_cast<const bf16x8*>(&Ks[kn * 16 + lr][lg * 8]);
          bf16x8 kf1 = *reinterpret_cast<const bf16x8*>(&Ks[kn * 16 + lr][32 + lg * 8]);
          zz = __builtin_amdgcn_mfma_f32_16x16x32_bf16(kf0, qf[0], zz, 0, 0, 0);
          zz = __builtin_amdgcn_mfma_f32_16x16x32_bf16(kf1, qf[1], zz, 0, 0, 0);
          sf[kn] = zz;
        }
        const bool needmask = (kb + 63 > qlo);
        float sc[4][4];
        float ml = -3.0e38f;
        for (int kn = 0; kn < 4; kn++) {
          float alib = slope2 * (float)(kb + kn * 16 + lg4);
          for (int j = 0; j < 4; j++) {
            float v = fmaf(sf[kn][j], sc2, alib + slope2 * (float)j);
            if (needmask && (kb + kn * 16 + lg4 + j > qa)) v = -3.0e38f;
            sc[kn][j] = v;
            ml = fmaxf(ml, v);
          }
        }
        ml = fmaxf(ml, __shfl_xor(ml, 16));
        ml = fmaxf(ml, __shfl_xor(ml, 32));
        float mnew = fmaxf(mrun, ml);
        float f = exp2f(mrun - mnew);
        float rs = 0.f;
        for (int kn = 0; kn < 4; kn++) {
          __bf16 pb[4];
          for (int j = 0; j < 4; j++) {
            float pv = exp2f(sc[kn][j] - mnew);
            rs += pv;
            pb[j] = (__bf16)pv;
          }
          *reinterpret_cast<uint2*>(&Pl[w][lr][kn * 16 + lg4]) =
              *reinterpret_cast<uint2*>(pb);
        }
        rs += __shfl_xor(rs, 16);
        rs += __shfl_xor(rs, 32);
        lrun = lrun * f + rs;
        mrun = mnew;
        float fj[4];
        for (int j = 0; j < 4; j++) fj[j] = __shfl(f, (lane & 48) | (lg4 + j));
        for (int dn = 0; dn < 4; dn++)
          for (int j = 0; j < 4; j++) accO[dn][j] *= fj[j];
        asm volatile("s_waitcnt lgkmcnt(0)" ::: "memory");
        for (int ks = 0; ks < 2; ks++) {
          bf16x8 pa = *reinterpret_cast<const bf16x8*>(&Pl[w][lr][ks * 32 + lg * 8]);
          for (int dn = 0; dn < 4; dn++) {
            int d = dn * 16 + lr;
            bf16x8 vb = *reinterpret_cast<const bf16x8*>(
                &Vt[d][(((ks * 4 + lg) ^ (d >> 3)) << 3)]);
            accO[dn] = __builtin_amdgcn_mfma_f32_16x16x32_bf16(pa, vb, accO[dn], 0, 0, 0);
          }
        }
      }
    }
    float linv[4];
    for (int j = 0; j < 4; j++)
      linv[j] = 1.f / __shfl(lrun, (lane & 48) | (lg4 + j));
    for (int dn = 0; dn < 4; dn++)
      for (int j = 0; j < 4; j++) {
        int row = qlo + lg4 + j;
        int d = dn * 16 + lr;
        o[(size_t)(b * 1024 + row) * 1024 + h * 64 + d] = f2b(accO[dn][j] * linv[j]);
      }
  }
}

// ---------------------------------------------------------------- decode GEMM (N=16) + transpose
__global__ __launch_bounds__(256) void k_dec(const unsigned short* __restrict__ xb,
                                             const unsigned short* __restrict__ dw,
                                             const float* __restrict__ db,
                                             float* __restrict__ out) {
  const int tid = threadIdx.x, lane = tid & 63, w = tid >> 6;
  const int lr = lane & 15, lg = lane >> 4;
  const int sb = blockIdx.x * 4 + w;
  const int r0 = sb * 16;
  f32x4 acc;
  for (int e = 0; e < 4; e++) acc[e] = 0.f;
  const unsigned short* arow = &xb[(size_t)(r0 + lr) * 1024];
  const unsigned short* brow = &dw[(size_t)lr * 1024];
  for (int k0 = 0; k0 < 1024; k0 += 32) {
    bf16x8 af = *reinterpret_cast<const bf16x8*>(arow + k0 + lg * 8);
    bf16x8 bf = *reinterpret_cast<const bf16x8*>(brow + k0 + lg * 8);
    acc = __builtin_amdgcn_mfma_f32_16x16x32_bf16(af, bf, acc, 0, 0, 0);
  }
  const int b = r0 >> 10;
  const int sl = (r0 & 1023) + lg * 4;
  float bias = db[lr];
  float4 res;
  res.x = acc[0] + bias; res.y = acc[1] + bias; res.z = acc[2] + bias; res.w = acc[3] + bias;
  *reinterpret_cast<float4*>(&out[(size_t)(b * 16 + lr) * 1024 + sl]) = res;
}

// ---------------------------------------------------------------- launcher
extern "C" void kernel_launch(void* const* d_in, const int* in_sizes, int n_in,
                              void* d_out, int out_size, void* d_ws, size_t ws_size,
                              hipStream_t stream) {
  (void)in_sizes; (void)n_in; (void)out_size;
  const float* z   = (const float*)d_in[0];
  const float* rt  = (const float*)d_in[1];
  const float* dnw = (const float*)d_in[2];
  const float* dnb = (const float*)d_in[3];
  const float* lng = (const float*)d_in[4];
  const float* lnb = (const float*)d_in[5];
  const float* wq  = (const float*)d_in[6];
  const float* bq  = (const float*)d_in[7];
  const float* wk  = (const float*)d_in[8];
  const float* bk  = (const float*)d_in[9];
  const float* wv  = (const float*)d_in[10];
  const float* bv  = (const float*)d_in[11];
  const float* wo  = (const float*)d_in[12];
  const float* bo  = (const float*)d_in[13];
  const float* dcw = (const float*)d_in[14];
  const float* dcb = (const float*)d_in[15];
  float* out = (float*)d_out;

  char* p = (char*)d_ws;
  float* x            = (float*)p;          p += (size_t)M * FDEC * 4;
  unsigned short* xin = (unsigned short*)p; p += (size_t)M * KP * 2;
  unsigned short* wdn = (unsigned short*)p; p += (size_t)FDEC * KP * 2;
  unsigned short* xn  = (unsigned short*)p; p += (size_t)M * FDEC * 2;
  unsigned short* w3  = (unsigned short*)p; p += (size_t)3 * FDEC * FDEC * 2;
  float* b3           = (float*)p;          p += (size_t)3 * FDEC * 4;
  unsigned short* qkv = (unsigned short*)p; p += (size_t)M * 3 * FDEC * 2;
  unsigned short* ob  = (unsigned short*)p; p += (size_t)M * FDEC * 2;
  unsigned short* wob = (unsigned short*)p; p += (size_t)FDEC * FDEC * 2;
  unsigned short* dwb = (unsigned short*)p; p += (size_t)FD * FDEC * 2;
  if ((size_t)(p - (char*)d_ws) > ws_size) return;

  k_prep_xin<<<(M * KP) / 256, 256, 0, stream>>>(z, rt, xin);
  k_cvt_pad<<<(FDEC * KP) / 256, 256, 0, stream>>>(dnw, wdn, FDEC, INK, KP);
  k_cvt_pad<<<(FDEC * FDEC) / 256, 256, 0, stream>>>(wq, w3, FDEC, FDEC, FDEC);
  k_cvt_pad<<<(FDEC * FDEC) / 256, 256, 0, stream>>>(wk, w3 + FDEC * FDEC, FDEC, FDEC, FDEC);
  k_cvt_pad<<<(FDEC * FDEC) / 256, 256, 0, stream>>>(wv, w3 + 2 * FDEC * FDEC, FDEC, FDEC, FDEC);
  k_cvt_pad<<<(FDEC * FDEC) / 256, 256, 0, stream>>>(wo, wob, FDEC, FDEC, FDEC);
  k_cvt_pad<<<(FD * FDEC) / 256, 256, 0, stream>>>(dcw, dwb, FD, FDEC, FDEC);
  k_b3<<<12, 256, 0, stream>>>(bq, bk, bv, b3);

  // dense + out-proj: r5 2-phase 256x128 (2 blk/CU). qkv: 4-phase 256x256.
  k_gemm2<0><<<(M / 256) * (FDEC / 128), 512, 0, stream>>>(xin, KP, wdn, KP, KP, FDEC, dnb, x, nullptr);
  k_ln<<<M, 256, 0, stream>>>(x, lng, lnb, xn);
  k_gemm4<1><<<(M / 256) * (3 * FDEC / 256), 512, 0, stream>>>(xn, FDEC, w3, FDEC, FDEC, 3 * FDEC, b3, nullptr, qkv);
  k_attn<<<dim3(Bn * H, 4), 512, 0, stream>>>(qkv, ob);
  k_gemm2<2><<<(M / 256) * (FDEC / 128), 512, 0, stream>>>(ob, FDEC, wob, FDEC, FDEC, FDEC, bo, x, xn);
  k_dec<<<M / 64, 256, 0, stream>>>(xn, dwb, dcb, out);
}

// Round 8
// 215.315 us; speedup vs baseline: 1.3920x; 1.2482x over previous
//
#include <hip/hip_runtime.h>

// ---------------------------------------------------------------- constants
static constexpr int Bn   = 8;
static constexpr int S    = 1024;
static constexpr int FT   = 16;
static constexpr int FDZ  = 768;
static constexpr int INK  = 784;   // FDZ + FT
static constexpr int KP   = 800;   // padded K for dense GEMM (25 * 32)
static constexpr int FDEC = 1024;
static constexpr int M    = Bn * S;   // 8192 rows
static constexpr int H    = 16;
static constexpr int FD   = 16;

typedef __bf16 bf16x8 __attribute__((ext_vector_type(8)));
typedef float  f32x4  __attribute__((ext_vector_type(4)));

__device__ __forceinline__ unsigned short f2b(float f) {
  return __builtin_bit_cast(unsigned short, static_cast<__bf16>(f));
}

__device__ __forceinline__ void gload16(const void* g, void* l) {
  __builtin_amdgcn_global_load_lds(
      (const __attribute__((address_space(1))) unsigned int*)g,
      (__attribute__((address_space(3))) unsigned int*)l, 16, 0, 0);
}

// ---------------------------------------------------------------- fused prep (1 launch)
// blocks: [0,8192) xin rows | [8192,9216) wdn rows | [9216,12288) w3 rows |
//         [12288,13312) wob | [13312,13328) dwb | [13328,13331) b3
__global__ __launch_bounds__(256) void k_prep(const float* __restrict__ z,
                                              const float* __restrict__ rt,
                                              const float* __restrict__ dnw,
                                              const float* __restrict__ wq,
                                              const float* __restrict__ wk,
                                              const float* __restrict__ wv,
                                              const float* __restrict__ wo,
                                              const float* __restrict__ dcw,
                                              const float* __restrict__ bq,
                                              const float* __restrict__ bk,
                                              const float* __restrict__ bv,
                                              unsigned short* __restrict__ xin,
                                              unsigned short* __restrict__ wdn,
                                              unsigned short* __restrict__ w3,
                                              unsigned short* __restrict__ wob,
                                              unsigned short* __restrict__ dwb,
                                              float* __restrict__ b3) {
  const int bid = blockIdx.x, tid = threadIdx.x;
  const int c = tid * 4;
  if (bid < 8192) {
    if (c >= KP) return;
    float4 v = make_float4(0.f, 0.f, 0.f, 0.f);
    if (c < FT)       v = *reinterpret_cast<const float4*>(&rt[bid * FT + c]);
    else if (c < INK) v = *reinterpret_cast<const float4*>(&z[(bid >> 10) * FDZ + c - FT]);
    unsigned short o4[4] = {f2b(v.x), f2b(v.y), f2b(v.z), f2b(v.w)};
    *reinterpret_cast<uint2*>(&xin[(size_t)bid * KP + c]) = *reinterpret_cast<uint2*>(o4);
  } else if (bid < 9216) {
    const int r = bid - 8192;
    if (c >= KP) return;
    float4 v = make_float4(0.f, 0.f, 0.f, 0.f);
    if (c < INK) v = *reinterpret_cast<const float4*>(&dnw[(size_t)r * INK + c]);
    unsigned short o4[4] = {f2b(v.x), f2b(v.y), f2b(v.z), f2b(v.w)};
    *reinterpret_cast<uint2*>(&wdn[(size_t)r * KP + c]) = *reinterpret_cast<uint2*>(o4);
  } else if (bid < 12288) {
    const int r = bid - 9216;
    const float* src = (r < 1024) ? wq : (r < 2048 ? wk : wv);
    const int rr = r & 1023;
    float4 v = *reinterpret_cast<const float4*>(&src[(size_t)rr * 1024 + c]);
    unsigned short o4[4] = {f2b(v.x), f2b(v.y), f2b(v.z), f2b(v.w)};
    *reinterpret_cast<uint2*>(&w3[(size_t)r * 1024 + c]) = *reinterpret_cast<uint2*>(o4);
  } else if (bid < 13312) {
    const int r = bid - 12288;
    float4 v = *reinterpret_cast<const float4*>(&wo[(size_t)r * 1024 + c]);
    unsigned short o4[4] = {f2b(v.x), f2b(v.y), f2b(v.z), f2b(v.w)};
    *reinterpret_cast<uint2*>(&wob[(size_t)r * 1024 + c]) = *reinterpret_cast<uint2*>(o4);
  } else if (bid < 13328) {
    const int r = bid - 13312;
    float4 v = *reinterpret_cast<const float4*>(&dcw[(size_t)r * 1024 + c]);
    unsigned short o4[4] = {f2b(v.x), f2b(v.y), f2b(v.z), f2b(v.w)};
    *reinterpret_cast<uint2*>(&dwb[(size_t)r * 1024 + c]) = *reinterpret_cast<uint2*>(o4);
  } else {
    const int r = bid - 13328;
    const float* s = (r == 0) ? bq : (r == 1 ? bk : bv);
    *reinterpret_cast<float4*>(&b3[r * 1024 + c]) =
        *reinterpret_cast<const float4*>(&s[c]);
  }
}

// ---------------------------------------------------------------- GEMM 2-phase 256x128 (qkv)
template<int EPI>
__global__ __launch_bounds__(512, 4) void k_gemm2(const unsigned short* __restrict__ A, int lda,
                                                  const unsigned short* __restrict__ Bw, int ldb,
                                                  int K, int N,
                                                  const float* __restrict__ bias,
                                                  float* __restrict__ Cf,
                                                  unsigned short* __restrict__ Cb) {
  __shared__ __align__(16) unsigned short As[3 * 256 * 32];   // 48 KiB
  __shared__ __align__(16) unsigned short Bs[3 * 128 * 32];   // 24 KiB
  const int tid = threadIdx.x, lane = tid & 63, w = tid >> 6;
  const int wr = w >> 1, wc = w & 1;
  const int lr = lane & 15, lg = lane >> 4;

  const int xcd = blockIdx.x & 7;
  const int j   = blockIdx.x >> 3;
  const int m0  = (xcd * 4 + (j & 3)) * 256;
  const int n0  = (j >> 2) * 128;

  const int nt = K >> 5;

  const int giA0 = w * 64 + lane;
  const int rA0 = giA0 >> 2, cA0 = (giA0 & 3) ^ ((rA0 >> 1) & 3);
  const int giA1 = 512 + w * 64 + lane;
  const int rA1 = giA1 >> 2, cA1 = (giA1 & 3) ^ ((rA1 >> 1) & 3);
  const int giB0 = w * 64 + lane;
  const int rB0 = giB0 >> 2, cB0 = (giB0 & 3) ^ ((rB0 >> 1) & 3);
  const unsigned short* srcA0 = A + (size_t)(m0 + rA0) * lda + cA0 * 8;
  const unsigned short* srcA1 = A + (size_t)(m0 + rA1) * lda + cA1 * 8;
  const unsigned short* srcB0 = Bw + (size_t)(n0 + rB0) * ldb + cB0 * 8;
  const int dA0 = (w * 64) * 8;
  const int dA1 = (512 + w * 64) * 8;
  const int dB0 = (w * 64) * 8;

  int offA[4], offB[4];
#pragma unroll
  for (int mi = 0; mi < 4; mi++) {
    int r = wr * 64 + mi * 16 + lr;
    offA[mi] = r * 32 + (lg ^ ((r >> 1) & 3)) * 8;
  }
#pragma unroll
  for (int ni = 0; ni < 4; ni++) {
    int r = wc * 64 + ni * 16 + lr;
    offB[ni] = r * 32 + (lg ^ ((r >> 1) & 3)) * 8;
  }

  f32x4 acc[4][4];
#pragma unroll
  for (int i = 0; i < 4; i++)
#pragma unroll
    for (int j2 = 0; j2 < 4; j2++)
#pragma unroll
      for (int e = 0; e < 4; e++) acc[i][j2][e] = 0.f;

  auto stage = [&](int tt) {
    const int sl = tt % 3;
    const size_t ko = (size_t)tt * 32;
    gload16(srcA0 + ko, &As[sl * 8192 + dA0]);
    gload16(srcA1 + ko, &As[sl * 8192 + dA1]);
    gload16(srcB0 + ko, &Bs[sl * 4096 + dB0]);
  };
  auto compute = [&](int tt) {
    const int sa = (tt % 3) * 8192;
    const int sb = (tt % 3) * 4096;
    bf16x8 af[4], bfr[4];
#pragma unroll
    for (int mi = 0; mi < 4; mi++)
      af[mi] = *reinterpret_cast<const bf16x8*>(&As[sa + offA[mi]]);
#pragma unroll
    for (int ni = 0; ni < 4; ni++)
      bfr[ni] = *reinterpret_cast<const bf16x8*>(&Bs[sb + offB[ni]]);
    __builtin_amdgcn_s_setprio(1);
#pragma unroll
    for (int mi = 0; mi < 4; mi++)
#pragma unroll
      for (int ni = 0; ni < 4; ni++)
        acc[mi][ni] = __builtin_amdgcn_mfma_f32_16x16x32_bf16(af[mi], bfr[ni], acc[mi][ni], 0, 0, 0);
    __builtin_amdgcn_s_setprio(0);
  };

  stage(0); stage(1);

  int t = 0;
  for (; t < nt - 2; ++t) {
    asm volatile("s_waitcnt vmcnt(3)" ::: "memory");
    __builtin_amdgcn_s_barrier();
    stage(t + 2);
    compute(t);
  }
  asm volatile("s_waitcnt vmcnt(3)" ::: "memory");
  __builtin_amdgcn_s_barrier();
  compute(t); ++t;
  asm volatile("s_waitcnt vmcnt(0)" ::: "memory");
  __builtin_amdgcn_s_barrier();
  compute(t);

#pragma unroll
  for (int mi = 0; mi < 4; mi++)
#pragma unroll
    for (int ni = 0; ni < 4; ni++) {
      int col = n0 + wc * 64 + ni * 16 + lr;
      float bv = bias ? bias[col] : 0.f;
#pragma unroll
      for (int jj = 0; jj < 4; jj++) {
        int row = m0 + wr * 64 + mi * 16 + lg * 4 + jj;
        float v = acc[mi][ni][jj] + bv;
        if constexpr (EPI == 0) {
          Cf[(size_t)row * N + col] = v;
        } else if constexpr (EPI == 1) {
          Cb[(size_t)row * N + col] = f2b(v);
        } else {
          size_t o = (size_t)row * N + col;
          float xv = Cf[o] + v;
          Cf[o] = xv;
          Cb[o] = f2b(xv);
        }
      }
    }
}

// ---------------------------------------------------------------- GEMM 128x128 (dense/out-proj)
// Same 3-slot/depth-2/counted-vmcnt/swizzle pattern; 256 thr (4 waves 2x2),
// 48 KiB LDS -> 3 blk/CU. Grid 512 -> full residency (k_gemm2 had 1 blk/CU here).
template<int EPI>
__global__ __launch_bounds__(256, 3) void k_gemm1(const unsigned short* __restrict__ A, int lda,
                                                  const unsigned short* __restrict__ Bw, int ldb,
                                                  int K, int N,
                                                  const float* __restrict__ bias,
                                                  float* __restrict__ Cf,
                                                  unsigned short* __restrict__ Cb) {
  __shared__ __align__(16) unsigned short As[3 * 128 * 32];   // 24 KiB
  __shared__ __align__(16) unsigned short Bs[3 * 128 * 32];   // 24 KiB
  const int tid = threadIdx.x, lane = tid & 63, w = tid >> 6;
  const int wr = w >> 1, wc = w & 1;
  const int lr = lane & 15, lg = lane >> 4;

  // XCD map: xcd owns m-tiles [8*xcd, 8*xcd+8) x all n (A-chunk 1024 rows -> L2)
  const int xcd = blockIdx.x & 7;
  const int j   = blockIdx.x >> 3;
  const int m0  = (xcd * 8 + (j & 7)) * 128;
  const int n0  = (j >> 3) * 128;

  const int nt = K >> 5;

  const int g0 = tid;
  const int r0g = g0 >> 2, c0g = (g0 & 3) ^ ((r0g >> 1) & 3);
  const int g1 = tid + 256;
  const int r1g = g1 >> 2, c1g = (g1 & 3) ^ ((r1g >> 1) & 3);
  const unsigned short* srcA0 = A + (size_t)(m0 + r0g) * lda + c0g * 8;
  const unsigned short* srcA1 = A + (size_t)(m0 + r1g) * lda + c1g * 8;
  const unsigned short* srcB0 = Bw + (size_t)(n0 + r0g) * ldb + c0g * 8;
  const unsigned short* srcB1 = Bw + (size_t)(n0 + r1g) * ldb + c1g * 8;
  const int d0 = (w * 64) * 8;          // waves 0..3 cover granules 0..255
  const int d1 = (256 + w * 64) * 8;    // and 256..511

  int offA[4], offB[4];
#pragma unroll
  for (int mi = 0; mi < 4; mi++) {
    int r = wr * 64 + mi * 16 + lr;
    offA[mi] = r * 32 + (lg ^ ((r >> 1) & 3)) * 8;
  }
#pragma unroll
  for (int ni = 0; ni < 4; ni++) {
    int r = wc * 64 + ni * 16 + lr;
    offB[ni] = r * 32 + (lg ^ ((r >> 1) & 3)) * 8;
  }

  f32x4 acc[4][4];
#pragma unroll
  for (int i = 0; i < 4; i++)
#pragma unroll
    for (int j2 = 0; j2 < 4; j2++)
#pragma unroll
      for (int e = 0; e < 4; e++) acc[i][j2][e] = 0.f;

  auto stage = [&](int tt) {
    const int sl = tt % 3;
    const size_t ko = (size_t)tt * 32;
    gload16(srcA0 + ko, &As[sl * 4096 + d0]);
    gload16(srcA1 + ko, &As[sl * 4096 + d1]);
    gload16(srcB0 + ko, &Bs[sl * 4096 + d0]);
    gload16(srcB1 + ko, &Bs[sl * 4096 + d1]);
  };
  auto compute = [&](int tt) {
    const int sl = (tt % 3) * 4096;
    bf16x8 af[4], bfr[4];
#pragma unroll
    for (int mi = 0; mi < 4; mi++)
      af[mi] = *reinterpret_cast<const bf16x8*>(&As[sl + offA[mi]]);
#pragma unroll
    for (int ni = 0; ni < 4; ni++)
      bfr[ni] = *reinterpret_cast<const bf16x8*>(&Bs[sl + offB[ni]]);
    __builtin_amdgcn_s_setprio(1);
#pragma unroll
    for (int mi = 0; mi < 4; mi++)
#pragma unroll
      for (int ni = 0; ni < 4; ni++)
        acc[mi][ni] = __builtin_amdgcn_mfma_f32_16x16x32_bf16(af[mi], bfr[ni], acc[mi][ni], 0, 0, 0);
    __builtin_amdgcn_s_setprio(0);
  };

  stage(0); stage(1);

  int t = 0;
  for (; t < nt - 2; ++t) {
    asm volatile("s_waitcnt vmcnt(4)" ::: "memory");   // tile t landed; t+1 in flight
    __builtin_amdgcn_s_barrier();
    stage(t + 2);
    compute(t);
  }
  asm volatile("s_waitcnt vmcnt(4)" ::: "memory");
  __builtin_amdgcn_s_barrier();
  compute(t); ++t;
  asm volatile("s_waitcnt vmcnt(0)" ::: "memory");
  __builtin_amdgcn_s_barrier();
  compute(t);

#pragma unroll
  for (int mi = 0; mi < 4; mi++)
#pragma unroll
    for (int ni = 0; ni < 4; ni++) {
      int col = n0 + wc * 64 + ni * 16 + lr;
      float bv = bias ? bias[col] : 0.f;
#pragma unroll
      for (int jj = 0; jj < 4; jj++) {
        int row = m0 + wr * 64 + mi * 16 + lg * 4 + jj;
        float v = acc[mi][ni][jj] + bv;
        if constexpr (EPI == 0) {
          Cf[(size_t)row * N + col] = v;
        } else if constexpr (EPI == 1) {
          Cb[(size_t)row * N + col] = f2b(v);
        } else {
          size_t o = (size_t)row * N + col;
          float xv = Cf[o] + v;
          Cf[o] = xv;
          Cb[o] = f2b(xv);
        }
      }
    }
}

// ---------------------------------------------------------------- LayerNorm (per row of 1024)
__global__ __launch_bounds__(256) void k_ln(const float* __restrict__ x,
                                            const float* __restrict__ g,
                                            const float* __restrict__ bta,
                                            unsigned short* __restrict__ xn) {
  int row = blockIdx.x;
  int tid = threadIdx.x;
  const float4 v = *reinterpret_cast<const float4*>(&x[(size_t)row * 1024 + tid * 4]);
  float s = v.x + v.y + v.z + v.w;
  float q = v.x * v.x + v.y * v.y + v.z * v.z + v.w * v.w;
  for (int off = 32; off; off >>= 1) { s += __shfl_down(s, off); q += __shfl_down(q, off); }
  __shared__ float ss[4], qq[4];
  int wid = tid >> 6, lane = tid & 63;
  if (lane == 0) { ss[wid] = s; qq[wid] = q; }
  __syncthreads();
  float St = ss[0] + ss[1] + ss[2] + ss[3];
  float Qt = qq[0] + qq[1] + qq[2] + qq[3];
  float mu  = St * (1.f / 1024.f);
  float var = Qt * (1.f / 1024.f) - mu * mu;
  float rstd = rsqrtf(var + 1e-6f);
  int c = tid * 4;
  unsigned short o[4];
  o[0] = f2b(g[c + 0] * (v.x - mu) * rstd + bta[c + 0]);
  o[1] = f2b(g[c + 1] * (v.y - mu) * rstd + bta[c + 1]);
  o[2] = f2b(g[c + 2] * (v.z - mu) * rstd + bta[c + 2]);
  o[3] = f2b(g[c + 3] * (v.w - mu) * rstd + bta[c + 3]);
  *reinterpret_cast<uint2*>(&xn[(size_t)row * 1024 + c]) = *reinterpret_cast<uint2*>(o);
}

// ---------------------------------------------------------------- flash attention
// grid (128 bh, 4 pairs); 512 thr = 8 waves x 16 q-rows; q-tiles {y, 7-y}.
// Swapped QK^T + in-register softmax (r3). NEW: double-buffered K/V LDS with
// ONE barrier per tile; staging writes for t+1 (regs loaded this iter) placed
// between softmax and PV, overlapped with compute. Buffer safety: buf[(t+1)&1]
// was last read in iter t-1, whose end-of-iter barrier precedes these writes.
__global__ __launch_bounds__(512, 4) void k_attn(const unsigned short* __restrict__ qkv,
                                                 unsigned short* __restrict__ o) {
  __shared__ unsigned short Ks[2][64][72];
  __shared__ unsigned short Vt[2][64][72];   // Vt[buf][d][swz(k)], swz: k-blk ^= (d>>3)
  __shared__ unsigned short Pl[8][16][72];
  const int tid = threadIdx.x, lane = tid & 63, w = tid >> 6;
  const int bh = blockIdx.x, b = bh >> 4, h = bh & 15;
  const int lr = lane & 15, lg = lane >> 4, lg4 = lg * 4;
  const int krow = tid >> 3, c8 = (tid & 7) << 3;
  const int kb8 = krow >> 3, kl = krow & 7, vq = tid & 7;
  const float slope2 = exp2f(-0.5f * (float)(h + 1)) * 1.44269504f;
  const float sc2 = 0.125f * 1.44269504f;

  for (int ph = 0; ph < 2; ++ph) {
    const int qb = ph ? (7 - (int)blockIdx.y) : (int)blockIdx.y;
    const int q0 = qb * 128;
    const int qlo = q0 + w * 16;
    const int qa = qlo + lr;

    bf16x8 qf0, qf1;
    {
      const unsigned short* qp = &qkv[(size_t)(b * 1024 + qlo + lr) * 3072 + h * 64];
      qf0 = *reinterpret_cast<const bf16x8*>(qp + lg * 8);
      qf1 = *reinterpret_cast<const bf16x8*>(qp + 32 + lg * 8);
    }
    float mrun = -3.0e38f, lrun = 0.f;
    f32x4 accO[4];
    for (int dn = 0; dn < 4; dn++)
      for (int e = 0; e < 4; e++) accO[dn][e] = 0.f;

    const int nt = 2 * qb + 2;
    uint4 kr, vr;
    {
      const size_t base = (size_t)(b * 1024 + krow) * 3072 + h * 64;
      kr = *reinterpret_cast<const uint4*>(&qkv[base + 1024 + c8]);
      vr = *reinterpret_cast<const uint4*>(&qkv[base + 2048 + c8]);
    }
    // initial fill of buf 0 (safe: previous loop ended with __syncthreads)
    *reinterpret_cast<uint4*>(&Ks[0][krow][c8]) = kr;
    {
      const unsigned short* vs = reinterpret_cast<const unsigned short*>(&vr);
      for (int jj = 0; jj < 8; jj++)
        Vt[0][c8 + jj][((kb8 ^ vq) << 3) | kl] = vs[jj];
    }
    __syncthreads();

    for (int kt = 0; kt < nt; ++kt) {
      const int kb = kt << 6;
      const int cb = kt & 1, nb = cb ^ 1;
      const bool hn = (kt + 1 < nt);
      if (hn) {                               // issue global loads for tile t+1
        const size_t base = (size_t)(b * 1024 + kb + 64 + krow) * 3072 + h * 64;
        kr = *reinterpret_cast<const uint4*>(&qkv[base + 1024 + c8]);
        vr = *reinterpret_cast<const uint4*>(&qkv[base + 2048 + c8]);
      }
      const bool act = (kb <= qlo + 15);      // wave-uniform skip of masked tile
      float f = 1.f;
      if (act) {
        f32x4 sf[4];
        for (int kn = 0; kn < 4; kn++) {
          f32x4 zz;
          for (int e = 0; e < 4; e++) zz[e] = 0.f;
          bf16x8 kf0 = *reinterpret_cast<const bf16x8*>(&Ks[cb][kn * 16 + lr][lg * 8]);
          bf16x8 kf1 = *reinterpret_cast<const bf16x8*>(&Ks[cb][kn * 16 + lr][32 + lg * 8]);
          zz = __builtin_amdgcn_mfma_f32_16x16x32_bf16(kf0, qf0, zz, 0, 0, 0);
          zz = __builtin_amdgcn_mfma_f32_16x16x32_bf16(kf1, qf1, zz, 0, 0, 0);
          sf[kn] = zz;
        }
        const bool needmask = (kb + 63 > qlo);
        float sc[4][4];
        float ml = -3.0e38f;
        for (int kn = 0; kn < 4; kn++) {
          float alib = slope2 * (float)(kb + kn * 16 + lg4);
          for (int jj = 0; jj < 4; jj++) {
            float v = fmaf(sf[kn][jj], sc2, alib + slope2 * (float)jj);
            if (needmask && (kb + kn * 16 + lg4 + jj > qa)) v = -3.0e38f;
            sc[kn][jj] = v;
            ml = fmaxf(ml, v);
          }
        }
        ml = fmaxf(ml, __shfl_xor(ml, 16));
        ml = fmaxf(ml, __shfl_xor(ml, 32));
        float mnew = fmaxf(mrun, ml);
        f = exp2f(mrun - mnew);
        float rs = 0.f;
        for (int kn = 0; kn < 4; kn++) {
          __bf16 pb[4];
          for (int jj = 0; jj < 4; jj++) {
            float pv = exp2f(sc[kn][jj] - mnew);
            rs += pv;
            pb[jj] = (__bf16)pv;
          }
          *reinterpret_cast<uint2*>(&Pl[w][lr][kn * 16 + lg4]) =
              *reinterpret_cast<uint2*>(pb);
        }
        rs += __shfl_xor(rs, 16);
        rs += __shfl_xor(rs, 32);
        lrun = lrun * f + rs;
        mrun = mnew;
      }
      if (hn) {                               // write buf for t+1 (overlapped)
        *reinterpret_cast<uint4*>(&Ks[nb][krow][c8]) = kr;
        const unsigned short* vs = reinterpret_cast<const unsigned short*>(&vr);
        for (int jj = 0; jj < 8; jj++)
          Vt[nb][c8 + jj][((kb8 ^ vq) << 3) | kl] = vs[jj];
      }
      if (act) {
        float fj[4];
        for (int jj = 0; jj < 4; jj++) fj[jj] = __shfl(f, (lane & 48) | (lg4 + jj));
        for (int dn = 0; dn < 4; dn++)
          for (int jj = 0; jj < 4; jj++) accO[dn][jj] *= fj[jj];
        asm volatile("s_waitcnt lgkmcnt(0)" ::: "memory");   // own P (+K/V) writes drained
        for (int ks = 0; ks < 2; ks++) {
          bf16x8 pa = *reinterpret_cast<const bf16x8*>(&Pl[w][lr][ks * 32 + lg * 8]);
          for (int dn = 0; dn < 4; dn++) {
            int d = dn * 16 + lr;
            bf16x8 vb = *reinterpret_cast<const bf16x8*>(
                &Vt[cb][d][(((ks * 4 + lg) ^ (d >> 3)) << 3)]);
            accO[dn] = __builtin_amdgcn_mfma_f32_16x16x32_bf16(pa, vb, accO[dn], 0, 0, 0);
          }
        }
      }
      __syncthreads();                        // single barrier per tile
    }
    float linv[4];
    for (int jj = 0; jj < 4; jj++)
      linv[jj] = 1.f / __shfl(lrun, (lane & 48) | (lg4 + jj));
    for (int dn = 0; dn < 4; dn++)
      for (int jj = 0; jj < 4; jj++) {
        int row = qlo + lg4 + jj;
        int d = dn * 16 + lr;
        o[(size_t)(b * 1024 + row) * 1024 + h * 64 + d] = f2b(accO[dn][jj] * linv[jj]);
      }
  }
}

// ---------------------------------------------------------------- decode GEMM (N=16) + transpose
__global__ __launch_bounds__(256) void k_dec(const unsigned short* __restrict__ xb,
                                             const unsigned short* __restrict__ dw,
                                             const float* __restrict__ db,
                                             float* __restrict__ out) {
  const int tid = threadIdx.x, lane = tid & 63, w = tid >> 6;
  const int lr = lane & 15, lg = lane >> 4;
  const int sb = blockIdx.x * 4 + w;
  const int r0 = sb * 16;
  f32x4 acc;
  for (int e = 0; e < 4; e++) acc[e] = 0.f;
  const unsigned short* arow = &xb[(size_t)(r0 + lr) * 1024];
  const unsigned short* brow = &dw[(size_t)lr * 1024];
  for (int k0 = 0; k0 < 1024; k0 += 32) {
    bf16x8 af = *reinterpret_cast<const bf16x8*>(arow + k0 + lg * 8);
    bf16x8 bf = *reinterpret_cast<const bf16x8*>(brow + k0 + lg * 8);
    acc = __builtin_amdgcn_mfma_f32_16x16x32_bf16(af, bf, acc, 0, 0, 0);
  }
  const int b = r0 >> 10;
  const int sl = (r0 & 1023) + lg * 4;
  float bias = db[lr];
  float4 res;
  res.x = acc[0] + bias; res.y = acc[1] + bias; res.z = acc[2] + bias; res.w = acc[3] + bias;
  *reinterpret_cast<float4*>(&out[(size_t)(b * 16 + lr) * 1024 + sl]) = res;
}

// ---------------------------------------------------------------- launcher
extern "C" void kernel_launch(void* const* d_in, const int* in_sizes, int n_in,
                              void* d_out, int out_size, void* d_ws, size_t ws_size,
                              hipStream_t stream) {
  (void)in_sizes; (void)n_in; (void)out_size;
  const float* z   = (const float*)d_in[0];
  const float* rt  = (const float*)d_in[1];
  const float* dnw = (const float*)d_in[2];
  const float* dnb = (const float*)d_in[3];
  const float* lng = (const float*)d_in[4];
  const float* lnb = (const float*)d_in[5];
  const float* wq  = (const float*)d_in[6];
  const float* bq  = (const float*)d_in[7];
  const float* wk  = (const float*)d_in[8];
  const float* bk  = (const float*)d_in[9];
  const float* wv  = (const float*)d_in[10];
  const float* bv  = (const float*)d_in[11];
  const float* wo  = (const float*)d_in[12];
  const float* bo  = (const float*)d_in[13];
  const float* dcw = (const float*)d_in[14];
  const float* dcb = (const float*)d_in[15];
  float* out = (float*)d_out;

  char* p = (char*)d_ws;
  float* x            = (float*)p;          p += (size_t)M * FDEC * 4;
  unsigned short* xin = (unsigned short*)p; p += (size_t)M * KP * 2;
  unsigned short* wdn = (unsigned short*)p; p += (size_t)FDEC * KP * 2;
  unsigned short* xn  = (unsigned short*)p; p += (size_t)M * FDEC * 2;
  unsigned short* w3  = (unsigned short*)p; p += (size_t)3 * FDEC * FDEC * 2;
  float* b3           = (float*)p;          p += (size_t)3 * FDEC * 4;
  unsigned short* qkv = (unsigned short*)p; p += (size_t)M * 3 * FDEC * 2;
  unsigned short* ob  = (unsigned short*)p; p += (size_t)M * FDEC * 2;
  unsigned short* wob = (unsigned short*)p; p += (size_t)FDEC * FDEC * 2;
  unsigned short* dwb = (unsigned short*)p; p += (size_t)FD * FDEC * 2;
  if ((size_t)(p - (char*)d_ws) > ws_size) return;

  k_prep<<<13331, 256, 0, stream>>>(z, rt, dnw, wq, wk, wv, wo, dcw, bq, bk, bv,
                                    xin, wdn, w3, wob, dwb, b3);

  k_gemm1<0><<<(M / 128) * (FDEC / 128), 256, 0, stream>>>(xin, KP, wdn, KP, KP, FDEC, dnb, x, nullptr);
  k_ln<<<M, 256, 0, stream>>>(x, lng, lnb, xn);
  k_gemm2<1><<<(M / 256) * (3 * FDEC / 128), 512, 0, stream>>>(xn, FDEC, w3, FDEC, FDEC, 3 * FDEC, b3, nullptr, qkv);
  k_attn<<<dim3(Bn * H, 4), 512, 0, stream>>>(qkv, ob);
  k_gemm1<2><<<(M / 128) * (FDEC / 128), 256, 0, stream>>>(ob, FDEC, wob, FDEC, FDEC, FDEC, bo, x, xn);
  k_dec<<<M / 64, 256, 0, stream>>>(xn, dwb, dcb, out);
}

// Round 9
// 185.462 us; speedup vs baseline: 1.6161x; 1.1610x over previous
//
#include <hip/hip_runtime.h>

// ---------------------------------------------------------------- constants
static constexpr int Bn   = 8;
static constexpr int S    = 1024;
static constexpr int FT   = 16;
static constexpr int FDZ  = 768;
static constexpr int INK  = 784;   // FDZ + FT
static constexpr int FDEC = 1024;
static constexpr int M    = Bn * S;   // 8192 rows
static constexpr int H    = 16;
static constexpr int FD   = 16;

typedef __bf16 bf16x8 __attribute__((ext_vector_type(8)));
typedef float  f32x4  __attribute__((ext_vector_type(4)));

__device__ __forceinline__ unsigned short f2b(float f) {
  return __builtin_bit_cast(unsigned short, static_cast<__bf16>(f));
}
__device__ __forceinline__ float b2f(unsigned short u) {
  return (float)__builtin_bit_cast(__bf16, u);
}

__device__ __forceinline__ void gload16(const void* g, void* l) {
  __builtin_amdgcn_global_load_lds(
      (const __attribute__((address_space(1))) unsigned int*)g,
      (__attribute__((address_space(3))) unsigned int*)l, 16, 0, 0);
}

// ---------------------------------------------------------------- fused prep (weights only)
// blocks: [0,3072) w3 | [3072,4096) wob | [4096,4112) dwb | [4112,4115) b3 |
//         [4115,4179) wt16 (dense_w[:, :16] transposed to [16][1024] bf16)
__global__ __launch_bounds__(256) void k_prep(const float* __restrict__ dnw,
                                              const float* __restrict__ wq,
                                              const float* __restrict__ wk,
                                              const float* __restrict__ wv,
                                              const float* __restrict__ wo,
                                              const float* __restrict__ dcw,
                                              const float* __restrict__ bq,
                                              const float* __restrict__ bk,
                                              const float* __restrict__ bv,
                                              unsigned short* __restrict__ w3,
                                              unsigned short* __restrict__ wob,
                                              unsigned short* __restrict__ dwb,
                                              float* __restrict__ b3,
                                              unsigned short* __restrict__ wt16) {
  const int bid = blockIdx.x, tid = threadIdx.x;
  const int c = tid * 4;
  if (bid < 3072) {
    const int r = bid;
    const float* src = (r < 1024) ? wq : (r < 2048 ? wk : wv);
    const int rr = r & 1023;
    float4 v = *reinterpret_cast<const float4*>(&src[(size_t)rr * 1024 + c]);
    unsigned short o4[4] = {f2b(v.x), f2b(v.y), f2b(v.z), f2b(v.w)};
    *reinterpret_cast<uint2*>(&w3[(size_t)r * 1024 + c]) = *reinterpret_cast<uint2*>(o4);
  } else if (bid < 4096) {
    const int r = bid - 3072;
    float4 v = *reinterpret_cast<const float4*>(&wo[(size_t)r * 1024 + c]);
    unsigned short o4[4] = {f2b(v.x), f2b(v.y), f2b(v.z), f2b(v.w)};
    *reinterpret_cast<uint2*>(&wob[(size_t)r * 1024 + c]) = *reinterpret_cast<uint2*>(o4);
  } else if (bid < 4112) {
    const int r = bid - 4096;
    float4 v = *reinterpret_cast<const float4*>(&dcw[(size_t)r * 1024 + c]);
    unsigned short o4[4] = {f2b(v.x), f2b(v.y), f2b(v.z), f2b(v.w)};
    *reinterpret_cast<uint2*>(&dwb[(size_t)r * 1024 + c]) = *reinterpret_cast<uint2*>(o4);
  } else if (bid < 4115) {
    const int r = bid - 4112;
    const float* s = (r == 0) ? bq : (r == 1 ? bk : bv);
    *reinterpret_cast<float4*>(&b3[r * 1024 + c]) =
        *reinterpret_cast<const float4*>(&s[c]);
  } else {
    const int idx = (bid - 4115) * 256 + tid;   // 0..16383
    const int k = idx >> 10, cc = idx & 1023;
    wt16[k * 1024 + cc] = f2b(dnw[(size_t)cc * INK + k]);
  }
}

// ---------------------------------------------------------------- za[b][col] = z[b] . dense_w[col][16:784]
// one wave per (col, b); lane-parallel over K=768, shuffle reduce.
__global__ __launch_bounds__(256) void k_za(const float* __restrict__ z,
                                            const float* __restrict__ dnw,
                                            float* __restrict__ za) {
  const int tid = threadIdx.x, lane = tid & 63, w = tid >> 6;
  const int idx = blockIdx.x * 4 + w;          // 0..8191
  const int col = idx >> 3, b = idx & 7;
  const float* wp = &dnw[(size_t)col * INK + FT];
  const float* zp = &z[b * FDZ];
  float s = 0.f;
#pragma unroll
  for (int i = 0; i < 12; i++) {
    int k = lane + i * 64;
    s += wp[k] * zp[k];
  }
  for (int off = 32; off; off >>= 1) s += __shfl_down(s, off);
  if (lane == 0) za[b * 1024 + col] = s;
}

// ---------------------------------------------------------------- fused dense(K=16) + LayerNorm
// grid 2048 x 256 thr, 4 rows/block. x[m][c] = rt[m].wt16[:,c] + za[b][c] + dnb[c];
// then LN over the row. Writes xres (x, bf16) and xn (normalized, bf16).
__global__ __launch_bounds__(256) void k_dense_ln(const float* __restrict__ rt,
                                                  const float* __restrict__ za,
                                                  const float* __restrict__ dnb,
                                                  const float* __restrict__ lng,
                                                  const float* __restrict__ lnb,
                                                  const unsigned short* __restrict__ wt16g,
                                                  unsigned short* __restrict__ xres,
                                                  unsigned short* __restrict__ xn) {
  __shared__ unsigned short wt[16 * 1024];     // [k][c] bf16, 32 KiB
  __shared__ float ss[4], qq[4];
  const int tid = threadIdx.x, lane = tid & 63, wv = tid >> 6;
  const int c0 = tid * 4;
#pragma unroll
  for (int i = 0; i < 8; i++)
    reinterpret_cast<uint4*>(wt)[tid + 256 * i] =
        reinterpret_cast<const uint4*>(wt16g)[tid + 256 * i];
  const float4 bv  = *reinterpret_cast<const float4*>(&dnb[c0]);
  const float4 gv  = *reinterpret_cast<const float4*>(&lng[c0]);
  const float4 bev = *reinterpret_cast<const float4*>(&lnb[c0]);
  __syncthreads();

  for (int r = 0; r < 4; ++r) {
    const int m = blockIdx.x * 4 + r;
    const int b = m >> 10;
    float rtv[16];
    {
      float4 t0 = *reinterpret_cast<const float4*>(&rt[m * 16 + 0]);
      float4 t1 = *reinterpret_cast<const float4*>(&rt[m * 16 + 4]);
      float4 t2 = *reinterpret_cast<const float4*>(&rt[m * 16 + 8]);
      float4 t3 = *reinterpret_cast<const float4*>(&rt[m * 16 + 12]);
      rtv[0]=t0.x; rtv[1]=t0.y; rtv[2]=t0.z; rtv[3]=t0.w;
      rtv[4]=t1.x; rtv[5]=t1.y; rtv[6]=t1.z; rtv[7]=t1.w;
      rtv[8]=t2.x; rtv[9]=t2.y; rtv[10]=t2.z; rtv[11]=t2.w;
      rtv[12]=t3.x; rtv[13]=t3.y; rtv[14]=t3.z; rtv[15]=t3.w;
    }
    float4 zav = *reinterpret_cast<const float4*>(&za[b * 1024 + c0]);
    float acc[4] = {zav.x + bv.x, zav.y + bv.y, zav.z + bv.z, zav.w + bv.w};
#pragma unroll
    for (int k = 0; k < 16; ++k) {
      uint2 wraw = *reinterpret_cast<const uint2*>(&wt[k * 1024 + c0]);
      const unsigned short* wp = reinterpret_cast<const unsigned short*>(&wraw);
      float rk = rtv[k];
      acc[0] += rk * b2f(wp[0]);
      acc[1] += rk * b2f(wp[1]);
      acc[2] += rk * b2f(wp[2]);
      acc[3] += rk * b2f(wp[3]);
    }
    float s = acc[0] + acc[1] + acc[2] + acc[3];
    float q = acc[0]*acc[0] + acc[1]*acc[1] + acc[2]*acc[2] + acc[3]*acc[3];
    for (int off = 32; off; off >>= 1) { s += __shfl_down(s, off); q += __shfl_down(q, off); }
    if (lane == 0) { ss[wv] = s; qq[wv] = q; }
    __syncthreads();
    float St = ss[0] + ss[1] + ss[2] + ss[3];
    float Qt = qq[0] + qq[1] + qq[2] + qq[3];
    float mu  = St * (1.f / 1024.f);
    float var = Qt * (1.f / 1024.f) - mu * mu;
    float rstd = rsqrtf(var + 1e-6f);
    unsigned short xo[4], no[4];
    xo[0] = f2b(acc[0]); no[0] = f2b(gv.x * (acc[0] - mu) * rstd + bev.x);
    xo[1] = f2b(acc[1]); no[1] = f2b(gv.y * (acc[1] - mu) * rstd + bev.y);
    xo[2] = f2b(acc[2]); no[2] = f2b(gv.z * (acc[2] - mu) * rstd + bev.z);
    xo[3] = f2b(acc[3]); no[3] = f2b(gv.w * (acc[3] - mu) * rstd + bev.w);
    *reinterpret_cast<uint2*>(&xres[(size_t)m * 1024 + c0]) = *reinterpret_cast<uint2*>(xo);
    *reinterpret_cast<uint2*>(&xn[(size_t)m * 1024 + c0])   = *reinterpret_cast<uint2*>(no);
    __syncthreads();   // ss/qq reuse next row
  }
}

// ---------------------------------------------------------------- GEMM 2-phase 256x128 (qkv)
template<int EPI>
__global__ __launch_bounds__(512, 4) void k_gemm2(const unsigned short* __restrict__ A, int lda,
                                                  const unsigned short* __restrict__ Bw, int ldb,
                                                  int K, int N,
                                                  const float* __restrict__ bias,
                                                  float* __restrict__ Cf,
                                                  unsigned short* __restrict__ Cb) {
  __shared__ __align__(16) unsigned short As[3 * 256 * 32];   // 48 KiB
  __shared__ __align__(16) unsigned short Bs[3 * 128 * 32];   // 24 KiB
  const int tid = threadIdx.x, lane = tid & 63, w = tid >> 6;
  const int wr = w >> 1, wc = w & 1;
  const int lr = lane & 15, lg = lane >> 4;

  const int xcd = blockIdx.x & 7;
  const int j   = blockIdx.x >> 3;
  const int m0  = (xcd * 4 + (j & 3)) * 256;
  const int n0  = (j >> 2) * 128;

  const int nt = K >> 5;

  const int giA0 = w * 64 + lane;
  const int rA0 = giA0 >> 2, cA0 = (giA0 & 3) ^ ((rA0 >> 1) & 3);
  const int giA1 = 512 + w * 64 + lane;
  const int rA1 = giA1 >> 2, cA1 = (giA1 & 3) ^ ((rA1 >> 1) & 3);
  const int giB0 = w * 64 + lane;
  const int rB0 = giB0 >> 2, cB0 = (giB0 & 3) ^ ((rB0 >> 1) & 3);
  const unsigned short* srcA0 = A + (size_t)(m0 + rA0) * lda + cA0 * 8;
  const unsigned short* srcA1 = A + (size_t)(m0 + rA1) * lda + cA1 * 8;
  const unsigned short* srcB0 = Bw + (size_t)(n0 + rB0) * ldb + cB0 * 8;
  const int dA0 = (w * 64) * 8;
  const int dA1 = (512 + w * 64) * 8;
  const int dB0 = (w * 64) * 8;

  int offA[4], offB[4];
#pragma unroll
  for (int mi = 0; mi < 4; mi++) {
    int r = wr * 64 + mi * 16 + lr;
    offA[mi] = r * 32 + (lg ^ ((r >> 1) & 3)) * 8;
  }
#pragma unroll
  for (int ni = 0; ni < 4; ni++) {
    int r = wc * 64 + ni * 16 + lr;
    offB[ni] = r * 32 + (lg ^ ((r >> 1) & 3)) * 8;
  }

  f32x4 acc[4][4];
#pragma unroll
  for (int i = 0; i < 4; i++)
#pragma unroll
    for (int j2 = 0; j2 < 4; j2++)
#pragma unroll
      for (int e = 0; e < 4; e++) acc[i][j2][e] = 0.f;

  auto stage = [&](int tt) {
    const int sl = tt % 3;
    const size_t ko = (size_t)tt * 32;
    gload16(srcA0 + ko, &As[sl * 8192 + dA0]);
    gload16(srcA1 + ko, &As[sl * 8192 + dA1]);
    gload16(srcB0 + ko, &Bs[sl * 4096 + dB0]);
  };
  auto compute = [&](int tt) {
    const int sa = (tt % 3) * 8192;
    const int sb = (tt % 3) * 4096;
    bf16x8 af[4], bfr[4];
#pragma unroll
    for (int mi = 0; mi < 4; mi++)
      af[mi] = *reinterpret_cast<const bf16x8*>(&As[sa + offA[mi]]);
#pragma unroll
    for (int ni = 0; ni < 4; ni++)
      bfr[ni] = *reinterpret_cast<const bf16x8*>(&Bs[sb + offB[ni]]);
    __builtin_amdgcn_s_setprio(1);
#pragma unroll
    for (int mi = 0; mi < 4; mi++)
#pragma unroll
      for (int ni = 0; ni < 4; ni++)
        acc[mi][ni] = __builtin_amdgcn_mfma_f32_16x16x32_bf16(af[mi], bfr[ni], acc[mi][ni], 0, 0, 0);
    __builtin_amdgcn_s_setprio(0);
  };

  stage(0); stage(1);

  int t = 0;
  for (; t < nt - 2; ++t) {
    asm volatile("s_waitcnt vmcnt(3)" ::: "memory");
    __builtin_amdgcn_s_barrier();
    stage(t + 2);
    compute(t);
  }
  asm volatile("s_waitcnt vmcnt(3)" ::: "memory");
  __builtin_amdgcn_s_barrier();
  compute(t); ++t;
  asm volatile("s_waitcnt vmcnt(0)" ::: "memory");
  __builtin_amdgcn_s_barrier();
  compute(t);

#pragma unroll
  for (int mi = 0; mi < 4; mi++)
#pragma unroll
    for (int ni = 0; ni < 4; ni++) {
      int col = n0 + wc * 64 + ni * 16 + lr;
      float bv = bias ? bias[col] : 0.f;
#pragma unroll
      for (int jj = 0; jj < 4; jj++) {
        int row = m0 + wr * 64 + mi * 16 + lg * 4 + jj;
        float v = acc[mi][ni][jj] + bv;
        if constexpr (EPI == 0) {
          Cf[(size_t)row * N + col] = v;
        } else {
          Cb[(size_t)row * N + col] = f2b(v);
        }
      }
    }
}

// ---------------------------------------------------------------- GEMM 128x128 (out-proj)
// 3 blk/CU; EPI 2: xn = bf16( bf16_res + acc + bias ), no fp32 round-trip.
template<int EPI>
__global__ __launch_bounds__(256, 3) void k_gemm1(const unsigned short* __restrict__ A, int lda,
                                                  const unsigned short* __restrict__ Bw, int ldb,
                                                  int K, int N,
                                                  const float* __restrict__ bias,
                                                  const unsigned short* __restrict__ res,
                                                  unsigned short* __restrict__ Cb) {
  __shared__ __align__(16) unsigned short As[3 * 128 * 32];   // 24 KiB
  __shared__ __align__(16) unsigned short Bs[3 * 128 * 32];   // 24 KiB
  const int tid = threadIdx.x, lane = tid & 63, w = tid >> 6;
  const int wr = w >> 1, wc = w & 1;
  const int lr = lane & 15, lg = lane >> 4;

  const int xcd = blockIdx.x & 7;
  const int j   = blockIdx.x >> 3;
  const int m0  = (xcd * 8 + (j & 7)) * 128;
  const int n0  = (j >> 3) * 128;

  const int nt = K >> 5;

  const int g0 = tid;
  const int r0g = g0 >> 2, c0g = (g0 & 3) ^ ((r0g >> 1) & 3);
  const int g1 = tid + 256;
  const int r1g = g1 >> 2, c1g = (g1 & 3) ^ ((r1g >> 1) & 3);
  const unsigned short* srcA0 = A + (size_t)(m0 + r0g) * lda + c0g * 8;
  const unsigned short* srcA1 = A + (size_t)(m0 + r1g) * lda + c1g * 8;
  const unsigned short* srcB0 = Bw + (size_t)(n0 + r0g) * ldb + c0g * 8;
  const unsigned short* srcB1 = Bw + (size_t)(n0 + r1g) * ldb + c1g * 8;
  const int d0 = (w * 64) * 8;
  const int d1 = (256 + w * 64) * 8;

  int offA[4], offB[4];
#pragma unroll
  for (int mi = 0; mi < 4; mi++) {
    int r = wr * 64 + mi * 16 + lr;
    offA[mi] = r * 32 + (lg ^ ((r >> 1) & 3)) * 8;
  }
#pragma unroll
  for (int ni = 0; ni < 4; ni++) {
    int r = wc * 64 + ni * 16 + lr;
    offB[ni] = r * 32 + (lg ^ ((r >> 1) & 3)) * 8;
  }

  f32x4 acc[4][4];
#pragma unroll
  for (int i = 0; i < 4; i++)
#pragma unroll
    for (int j2 = 0; j2 < 4; j2++)
#pragma unroll
      for (int e = 0; e < 4; e++) acc[i][j2][e] = 0.f;

  auto stage = [&](int tt) {
    const int sl = tt % 3;
    const size_t ko = (size_t)tt * 32;
    gload16(srcA0 + ko, &As[sl * 4096 + d0]);
    gload16(srcA1 + ko, &As[sl * 4096 + d1]);
    gload16(srcB0 + ko, &Bs[sl * 4096 + d0]);
    gload16(srcB1 + ko, &Bs[sl * 4096 + d1]);
  };
  auto compute = [&](int tt) {
    const int sl = (tt % 3) * 4096;
    bf16x8 af[4], bfr[4];
#pragma unroll
    for (int mi = 0; mi < 4; mi++)
      af[mi] = *reinterpret_cast<const bf16x8*>(&As[sl + offA[mi]]);
#pragma unroll
    for (int ni = 0; ni < 4; ni++)
      bfr[ni] = *reinterpret_cast<const bf16x8*>(&Bs[sl + offB[ni]]);
    __builtin_amdgcn_s_setprio(1);
#pragma unroll
    for (int mi = 0; mi < 4; mi++)
#pragma unroll
      for (int ni = 0; ni < 4; ni++)
        acc[mi][ni] = __builtin_amdgcn_mfma_f32_16x16x32_bf16(af[mi], bfr[ni], acc[mi][ni], 0, 0, 0);
    __builtin_amdgcn_s_setprio(0);
  };

  stage(0); stage(1);

  int t = 0;
  for (; t < nt - 2; ++t) {
    asm volatile("s_waitcnt vmcnt(4)" ::: "memory");
    __builtin_amdgcn_s_barrier();
    stage(t + 2);
    compute(t);
  }
  asm volatile("s_waitcnt vmcnt(4)" ::: "memory");
  __builtin_amdgcn_s_barrier();
  compute(t); ++t;
  asm volatile("s_waitcnt vmcnt(0)" ::: "memory");
  __builtin_amdgcn_s_barrier();
  compute(t);

#pragma unroll
  for (int mi = 0; mi < 4; mi++)
#pragma unroll
    for (int ni = 0; ni < 4; ni++) {
      int col = n0 + wc * 64 + ni * 16 + lr;
      float bv = bias ? bias[col] : 0.f;
#pragma unroll
      for (int jj = 0; jj < 4; jj++) {
        int row = m0 + wr * 64 + mi * 16 + lg * 4 + jj;
        float v = acc[mi][ni][jj] + bv;
        size_t o = (size_t)row * N + col;
        if constexpr (EPI == 2) {
          Cb[o] = f2b(b2f(res[o]) + v);
        } else {
          Cb[o] = f2b(v);
        }
      }
    }
}

// ---------------------------------------------------------------- flash attention (r8, unchanged)
__global__ __launch_bounds__(512, 4) void k_attn(const unsigned short* __restrict__ qkv,
                                                 unsigned short* __restrict__ o) {
  __shared__ unsigned short Ks[2][64][72];
  __shared__ unsigned short Vt[2][64][72];
  __shared__ unsigned short Pl[8][16][72];
  const int tid = threadIdx.x, lane = tid & 63, w = tid >> 6;
  const int bh = blockIdx.x, b = bh >> 4, h = bh & 15;
  const int lr = lane & 15, lg = lane >> 4, lg4 = lg * 4;
  const int krow = tid >> 3, c8 = (tid & 7) << 3;
  const int kb8 = krow >> 3, kl = krow & 7, vq = tid & 7;
  const float slope2 = exp2f(-0.5f * (float)(h + 1)) * 1.44269504f;
  const float sc2 = 0.125f * 1.44269504f;

  for (int ph = 0; ph < 2; ++ph) {
    const int qb = ph ? (7 - (int)blockIdx.y) : (int)blockIdx.y;
    const int q0 = qb * 128;
    const int qlo = q0 + w * 16;
    const int qa = qlo + lr;

    bf16x8 qf0, qf1;
    {
      const unsigned short* qp = &qkv[(size_t)(b * 1024 + qlo + lr) * 3072 + h * 64];
      qf0 = *reinterpret_cast<const bf16x8*>(qp + lg * 8);
      qf1 = *reinterpret_cast<const bf16x8*>(qp + 32 + lg * 8);
    }
    float mrun = -3.0e38f, lrun = 0.f;
    f32x4 accO[4];
    for (int dn = 0; dn < 4; dn++)
      for (int e = 0; e < 4; e++) accO[dn][e] = 0.f;

    const int nt = 2 * qb + 2;
    uint4 kr, vr;
    {
      const size_t base = (size_t)(b * 1024 + krow) * 3072 + h * 64;
      kr = *reinterpret_cast<const uint4*>(&qkv[base + 1024 + c8]);
      vr = *reinterpret_cast<const uint4*>(&qkv[base + 2048 + c8]);
    }
    *reinterpret_cast<uint4*>(&Ks[0][krow][c8]) = kr;
    {
      const unsigned short* vs = reinterpret_cast<const unsigned short*>(&vr);
      for (int jj = 0; jj < 8; jj++)
        Vt[0][c8 + jj][((kb8 ^ vq) << 3) | kl] = vs[jj];
    }
    __syncthreads();

    for (int kt = 0; kt < nt; ++kt) {
      const int kb = kt << 6;
      const int cb = kt & 1, nb = cb ^ 1;
      const bool hn = (kt + 1 < nt);
      if (hn) {
        const size_t base = (size_t)(b * 1024 + kb + 64 + krow) * 3072 + h * 64;
        kr = *reinterpret_cast<const uint4*>(&qkv[base + 1024 + c8]);
        vr = *reinterpret_cast<const uint4*>(&qkv[base + 2048 + c8]);
      }
      const bool act = (kb <= qlo + 15);
      float f = 1.f;
      if (act) {
        f32x4 sf[4];
        for (int kn = 0; kn < 4; kn++) {
          f32x4 zz;
          for (int e = 0; e < 4; e++) zz[e] = 0.f;
          bf16x8 kf0 = *reinterpret_cast<const bf16x8*>(&Ks[cb][kn * 16 + lr][lg * 8]);
          bf16x8 kf1 = *reinterpret_cast<const bf16x8*>(&Ks[cb][kn * 16 + lr][32 + lg * 8]);
          zz = __builtin_amdgcn_mfma_f32_16x16x32_bf16(kf0, qf0, zz, 0, 0, 0);
          zz = __builtin_amdgcn_mfma_f32_16x16x32_bf16(kf1, qf1, zz, 0, 0, 0);
          sf[kn] = zz;
        }
        const bool needmask = (kb + 63 > qlo);
        float sc[4][4];
        float ml = -3.0e38f;
        for (int kn = 0; kn < 4; kn++) {
          float alib = slope2 * (float)(kb + kn * 16 + lg4);
          for (int jj = 0; jj < 4; jj++) {
            float v = fmaf(sf[kn][jj], sc2, alib + slope2 * (float)jj);
            if (needmask && (kb + kn * 16 + lg4 + jj > qa)) v = -3.0e38f;
            sc[kn][jj] = v;
            ml = fmaxf(ml, v);
          }
        }
        ml = fmaxf(ml, __shfl_xor(ml, 16));
        ml = fmaxf(ml, __shfl_xor(ml, 32));
        float mnew = fmaxf(mrun, ml);
        f = exp2f(mrun - mnew);
        float rs = 0.f;
        for (int kn = 0; kn < 4; kn++) {
          __bf16 pb[4];
          for (int jj = 0; jj < 4; jj++) {
            float pv = exp2f(sc[kn][jj] - mnew);
            rs += pv;
            pb[jj] = (__bf16)pv;
          }
          *reinterpret_cast<uint2*>(&Pl[w][lr][kn * 16 + lg4]) =
              *reinterpret_cast<uint2*>(pb);
        }
        rs += __shfl_xor(rs, 16);
        rs += __shfl_xor(rs, 32);
        lrun = lrun * f + rs;
        mrun = mnew;
      }
      if (hn) {
        *reinterpret_cast<uint4*>(&Ks[nb][krow][c8]) = kr;
        const unsigned short* vs = reinterpret_cast<const unsigned short*>(&vr);
        for (int jj = 0; jj < 8; jj++)
          Vt[nb][c8 + jj][((kb8 ^ vq) << 3) | kl] = vs[jj];
      }
      if (act) {
        float fj[4];
        for (int jj = 0; jj < 4; jj++) fj[jj] = __shfl(f, (lane & 48) | (lg4 + jj));
        for (int dn = 0; dn < 4; dn++)
          for (int jj = 0; jj < 4; jj++) accO[dn][jj] *= fj[jj];
        asm volatile("s_waitcnt lgkmcnt(0)" ::: "memory");
        for (int ks = 0; ks < 2; ks++) {
          bf16x8 pa = *reinterpret_cast<const bf16x8*>(&Pl[w][lr][ks * 32 + lg * 8]);
          for (int dn = 0; dn < 4; dn++) {
            int d = dn * 16 + lr;
            bf16x8 vb = *reinterpret_cast<const bf16x8*>(
                &Vt[cb][d][(((ks * 4 + lg) ^ (d >> 3)) << 3)]);
            accO[dn] = __builtin_amdgcn_mfma_f32_16x16x32_bf16(pa, vb, accO[dn], 0, 0, 0);
          }
        }
      }
      __syncthreads();
    }
    float linv[4];
    for (int jj = 0; jj < 4; jj++)
      linv[jj] = 1.f / __shfl(lrun, (lane & 48) | (lg4 + jj));
    for (int dn = 0; dn < 4; dn++)
      for (int jj = 0; jj < 4; jj++) {
        int row = qlo + lg4 + jj;
        int d = dn * 16 + lr;
        o[(size_t)(b * 1024 + row) * 1024 + h * 64 + d] = f2b(accO[dn][jj] * linv[jj]);
      }
  }
}

// ---------------------------------------------------------------- decode GEMM (N=16) + transpose
__global__ __launch_bounds__(256) void k_dec(const unsigned short* __restrict__ xb,
                                             const unsigned short* __restrict__ dw,
                                             const float* __restrict__ db,
                                             float* __restrict__ out) {
  const int tid = threadIdx.x, lane = tid & 63, w = tid >> 6;
  const int lr = lane & 15, lg = lane >> 4;
  const int sb = blockIdx.x * 4 + w;
  const int r0 = sb * 16;
  f32x4 acc;
  for (int e = 0; e < 4; e++) acc[e] = 0.f;
  const unsigned short* arow = &xb[(size_t)(r0 + lr) * 1024];
  const unsigned short* brow = &dw[(size_t)lr * 1024];
  for (int k0 = 0; k0 < 1024; k0 += 32) {
    bf16x8 af = *reinterpret_cast<const bf16x8*>(arow + k0 + lg * 8);
    bf16x8 bf = *reinterpret_cast<const bf16x8*>(brow + k0 + lg * 8);
    acc = __builtin_amdgcn_mfma_f32_16x16x32_bf16(af, bf, acc, 0, 0, 0);
  }
  const int b = r0 >> 10;
  const int sl = (r0 & 1023) + lg * 4;
  float bias = db[lr];
  float4 res;
  res.x = acc[0] + bias; res.y = acc[1] + bias; res.z = acc[2] + bias; res.w = acc[3] + bias;
  *reinterpret_cast<float4*>(&out[(size_t)(b * 16 + lr) * 1024 + sl]) = res;
}

// ---------------------------------------------------------------- launcher
extern "C" void kernel_launch(void* const* d_in, const int* in_sizes, int n_in,
                              void* d_out, int out_size, void* d_ws, size_t ws_size,
                              hipStream_t stream) {
  (void)in_sizes; (void)n_in; (void)out_size;
  const float* z   = (const float*)d_in[0];
  const float* rt  = (const float*)d_in[1];
  const float* dnw = (const float*)d_in[2];
  const float* dnb = (const float*)d_in[3];
  const float* lng = (const float*)d_in[4];
  const float* lnb = (const float*)d_in[5];
  const float* wq  = (const float*)d_in[6];
  const float* bq  = (const float*)d_in[7];
  const float* wk  = (const float*)d_in[8];
  const float* bk  = (const float*)d_in[9];
  const float* wv  = (const float*)d_in[10];
  const float* bv  = (const float*)d_in[11];
  const float* wo  = (const float*)d_in[12];
  const float* bo  = (const float*)d_in[13];
  const float* dcw = (const float*)d_in[14];
  const float* dcb = (const float*)d_in[15];
  float* out = (float*)d_out;

  char* p = (char*)d_ws;
  unsigned short* xres = (unsigned short*)p; p += (size_t)M * FDEC * 2;
  unsigned short* xn   = (unsigned short*)p; p += (size_t)M * FDEC * 2;
  unsigned short* w3   = (unsigned short*)p; p += (size_t)3 * FDEC * FDEC * 2;
  float* b3            = (float*)p;          p += (size_t)3 * FDEC * 4;
  unsigned short* qkv  = (unsigned short*)p; p += (size_t)M * 3 * FDEC * 2;
  unsigned short* ob   = (unsigned short*)p; p += (size_t)M * FDEC * 2;
  unsigned short* wob  = (unsigned short*)p; p += (size_t)FDEC * FDEC * 2;
  unsigned short* dwb  = (unsigned short*)p; p += (size_t)FD * FDEC * 2;
  float* za            = (float*)p;          p += (size_t)8 * 1024 * 4;
  unsigned short* wt16 = (unsigned short*)p; p += (size_t)16 * 1024 * 2;
  if ((size_t)(p - (char*)d_ws) > ws_size) return;

  k_prep<<<4179, 256, 0, stream>>>(dnw, wq, wk, wv, wo, dcw, bq, bk, bv,
                                   w3, wob, dwb, b3, wt16);
  k_za<<<2048, 256, 0, stream>>>(z, dnw, za);
  k_dense_ln<<<2048, 256, 0, stream>>>(rt, za, dnb, lng, lnb, wt16, xres, xn);
  k_gemm2<1><<<(M / 256) * (3 * FDEC / 128), 512, 0, stream>>>(xn, FDEC, w3, FDEC, FDEC, 3 * FDEC, b3, nullptr, qkv);
  k_attn<<<dim3(Bn * H, 4), 512, 0, stream>>>(qkv, ob);
  k_gemm1<2><<<(M / 128) * (FDEC / 128), 256, 0, stream>>>(ob, FDEC, wob, FDEC, FDEC, FDEC, bo, xres, xn);
  k_dec<<<M / 64, 256, 0, stream>>>(xn, dwb, dcb, out);
}